// Round 1
// baseline (783.068 us; speedup 1.0000x reference)
//
#include <hip/hip_runtime.h>
#include <stdint.h>
#include <stdio.h>

#define T_TOK 4096
#define DMODEL 2048
#define NEXP 8
#define DFF 1408
#define DFFS 2816
#define NSLOT 8192   // T_TOK * 2

typedef unsigned short u16;
typedef short s16x8 __attribute__((ext_vector_type(8)));
typedef unsigned short u16x4 __attribute__((ext_vector_type(4)));
typedef __bf16 bf16x8 __attribute__((ext_vector_type(8)));
typedef float f32x4 __attribute__((ext_vector_type(4)));

__device__ __forceinline__ u16 f2bf(float f) {
  uint32_t u = __builtin_bit_cast(uint32_t, f);
  u += 0x7fffu + ((u >> 16) & 1u);
  return (u16)(u >> 16);
}
__device__ __forceinline__ float bf2f(u16 h) {
  uint32_t u = ((uint32_t)h) << 16;
  return __builtin_bit_cast(float, u);
}

// ---------------- fp32 -> bf16 convert (4 elems/thread) ----------------
__global__ void k_convert(const float* __restrict__ in, u16* __restrict__ out, int n4) {
  int i = blockIdx.x * 256 + threadIdx.x;
  if (i >= n4) return;
  float4 v = ((const float4*)in)[i];
  u16x4 r = { f2bf(v.x), f2bf(v.y), f2bf(v.z), f2bf(v.w) };
  ((u16x4*)out)[i] = r;
}

// ---------------- zero counts ----------------
__global__ void k_zero(int* __restrict__ counts) {
  if (threadIdx.x < NEXP) counts[threadIdx.x] = 0;
}

// ---------------- router: one wave per token, f64 accumulation ----------------
__global__ void k_router(const float* __restrict__ x, const float* __restrict__ gw,
                         float* __restrict__ tkw, int* __restrict__ tki,
                         int* __restrict__ counts) {
  int t = blockIdx.x;
  int lane = threadIdx.x;
  const float* xr = x + (size_t)t * DMODEL;
  double acc[NEXP];
#pragma unroll
  for (int e = 0; e < NEXP; ++e) acc[e] = 0.0;
  for (int d = lane; d < DMODEL; d += 64) {
    float xv = xr[d];
#pragma unroll
    for (int e = 0; e < NEXP; ++e)
      acc[e] += (double)xv * (double)gw[e * DMODEL + d];
  }
#pragma unroll
  for (int e = 0; e < NEXP; ++e) {
#pragma unroll
    for (int off = 32; off; off >>= 1) acc[e] += __shfl_down(acc[e], off, 64);
  }
  if (lane == 0) {
    int i0 = 0; double v0 = acc[0];
    for (int e = 1; e < NEXP; ++e) if (acc[e] > v0) { v0 = acc[e]; i0 = e; }
    int i1 = -1; double v1 = -1e300;
    for (int e = 0; e < NEXP; ++e) if (e != i0 && acc[e] > v1) { v1 = acc[e]; i1 = e; }
    double r = exp(v1 - v0);              // <= 1
    float w0 = (float)(1.0 / (1.0 + r));
    float w1 = 1.0f - w0;
    tkw[2 * t] = w0; tkw[2 * t + 1] = w1;
    tki[2 * t] = i0; tki[2 * t + 1] = i1;
    atomicAdd(&counts[i0], 1);
    atomicAdd(&counts[i1], 1);
  }
}

// ---------------- exclusive scan over 8 experts ----------------
__global__ void k_scan(const int* __restrict__ counts, int* __restrict__ offs,
                       int* __restrict__ cursor) {
  if (threadIdx.x == 0) {
    int s = 0;
    for (int e = 0; e < NEXP; ++e) { offs[e] = s; cursor[e] = s; s += counts[e]; }
    offs[NEXP] = s;
  }
}

// ---------------- assign compacted slots ----------------
__global__ void k_assign(const int* __restrict__ tki, int* __restrict__ cursor,
                         int* __restrict__ pos, int* __restrict__ slot_tok) {
  int t = blockIdx.x * 256 + threadIdx.x;
  if (t >= T_TOK) return;
#pragma unroll
  for (int k = 0; k < 2; ++k) {
    int e = tki[2 * t + k];
    int p = atomicAdd(&cursor[e], 1);
    pos[2 * t + k] = p;
    slot_tok[p] = t;
  }
}

// ---------------- NT bf16 GEMM: C[M,N] = A[M,K] * B[N,K]^T ----------------
// 128x128 tile, BK=64, 4 waves (2x2 of 64x64), 16x16x32 MFMA.
// Reg-staged LDS with +8 padding (stride 72) -> conflict-free ds_read_b128.
template <int KD, bool PEREXP, bool GATHER, bool OUTF32>
__launch_bounds__(256, 2)
__global__ void k_gemm(const u16* __restrict__ A, const u16* __restrict__ B,
                       size_t b_estride, void* __restrict__ C, int N,
                       const int* __restrict__ offs, const int* __restrict__ counts,
                       const int* __restrict__ slot_tok, int m_total) {
  constexpr int BM = 128, BN = 128, BK = 64, LDP = 72;
  __shared__ __attribute__((aligned(16))) u16 As[BM][LDP];
  __shared__ __attribute__((aligned(16))) u16 Bs[BN][LDP];

  int e, base, cnt;
  if constexpr (PEREXP) {
    e = blockIdx.z; base = offs[e]; cnt = counts[e];
  } else {
    e = 0; base = 0; cnt = m_total;
  }
  int m0 = blockIdx.y * BM;
  if (m0 >= cnt) return;
  int n0 = blockIdx.x * BN;

  int tid = threadIdx.x;
  int rsub = tid >> 3;   // 0..31: row within 32-row staging group
  int c16 = tid & 7;     // 16-byte chunk within 128B row

  const u16* arow[4];
  const u16* brow[4];
#pragma unroll
  for (int p = 0; p < 4; ++p) {
    int r = m0 + p * 32 + rsub;
    int rc = r < cnt ? r : (cnt - 1);
    int ga;
    if constexpr (GATHER) ga = slot_tok[base + rc];
    else                  ga = base + rc;
    arow[p] = A + (size_t)ga * KD;
    brow[p] = B + b_estride * (size_t)e + (size_t)(n0 + p * 32 + rsub) * KD;
  }

  int lane = tid & 63;
  int wv = tid >> 6;
  int wr = (wv >> 1) * 64, wc = (wv & 1) * 64;
  int fr = lane & 15, fq = lane >> 4;

  f32x4 zero = {0.f, 0.f, 0.f, 0.f};
  f32x4 acc[4][4];
#pragma unroll
  for (int i = 0; i < 4; ++i)
#pragma unroll
    for (int j = 0; j < 4; ++j) acc[i][j] = zero;

  for (int k0 = 0; k0 < KD; k0 += BK) {
    s16x8 av[4], bv[4];
#pragma unroll
    for (int p = 0; p < 4; ++p) {
      av[p] = *(const s16x8*)(arow[p] + k0 + c16 * 8);
      bv[p] = *(const s16x8*)(brow[p] + k0 + c16 * 8);
    }
    __syncthreads();   // previous iter's LDS reads done
#pragma unroll
    for (int p = 0; p < 4; ++p) {
      *(s16x8*)&As[p * 32 + rsub][c16 * 8] = av[p];
      *(s16x8*)&Bs[p * 32 + rsub][c16 * 8] = bv[p];
    }
    __syncthreads();   // LDS tile ready
#pragma unroll
    for (int ks = 0; ks < 2; ++ks) {
      bf16x8 af[4], bfv[4];
#pragma unroll
      for (int i = 0; i < 4; ++i) {
        af[i]  = *(const bf16x8*)&As[wr + i * 16 + fr][ks * 32 + fq * 8];
        bfv[i] = *(const bf16x8*)&Bs[wc + i * 16 + fr][ks * 32 + fq * 8];
      }
#pragma unroll
      for (int i = 0; i < 4; ++i)
#pragma unroll
        for (int j = 0; j < 4; ++j)
          acc[i][j] = __builtin_amdgcn_mfma_f32_16x16x32_bf16(af[i], bfv[j], acc[i][j], 0, 0, 0);
    }
  }

  // epilogue: C row = base+m (compacted), col = n0 + ...
#pragma unroll
  for (int i = 0; i < 4; ++i) {
    int rl = wr + i * 16 + fq * 4;
#pragma unroll
    for (int j = 0; j < 4; ++j) {
      int col = n0 + wc + j * 16 + fr;
#pragma unroll
      for (int r = 0; r < 4; ++r) {
        int m = m0 + rl + r;
        if (m < cnt) {
          size_t off = (size_t)(base + m) * (size_t)N + (size_t)col;
          if constexpr (OUTF32) ((float*)C)[off] = acc[i][j][r];
          else                  ((u16*)C)[off] = f2bf(acc[i][j][r]);
        }
      }
    }
  }
}

// ---------------- h = silu(g) * u, 8 elems/thread ----------------
__global__ void k_silu_mul(const u16* __restrict__ g, const u16* __restrict__ u,
                           u16* __restrict__ h, int n8) {
  int i = blockIdx.x * 256 + threadIdx.x;
  if (i >= n8) return;
  s16x8 gv = ((const s16x8*)g)[i];
  s16x8 uv = ((const s16x8*)u)[i];
  s16x8 hv;
#pragma unroll
  for (int j = 0; j < 8; ++j) {
    float gf = bf2f((u16)gv[j]);
    float uf = bf2f((u16)uv[j]);
    float s = gf / (1.f + __expf(-gf));
    hv[j] = (short)f2bf(s * uf);
  }
  ((s16x8*)h)[i] = hv;
}

// ---------------- y[t] += w0*yr[pos0] + w1*yr[pos1] ----------------
__global__ void k_combine(float* __restrict__ y, const u16* __restrict__ yr,
                          const float* __restrict__ tkw, const int* __restrict__ pos) {
  int t = blockIdx.x;
  int i = threadIdx.x;
  float w0 = tkw[2 * t], w1 = tkw[2 * t + 1];
  size_t p0 = (size_t)pos[2 * t] * DMODEL, p1 = (size_t)pos[2 * t + 1] * DMODEL;
  int d0 = i * 8;
  s16x8 a = *(const s16x8*)(yr + p0 + d0);
  s16x8 b = *(const s16x8*)(yr + p1 + d0);
  float* yo = y + (size_t)t * DMODEL + d0;
#pragma unroll
  for (int j = 0; j < 8; ++j)
    yo[j] += w0 * bf2f((u16)a[j]) + w1 * bf2f((u16)b[j]);
}

extern "C" void kernel_launch(void* const* d_in, const int* in_sizes, int n_in,
                              void* d_out, int out_size, void* d_ws, size_t ws_size,
                              hipStream_t stream) {
  const float* x   = (const float*)d_in[0];
  const float* gw  = (const float*)d_in[1];
  const float* wg  = (const float*)d_in[2];
  const float* wu  = (const float*)d_in[3];
  const float* wd  = (const float*)d_in[4];
  const float* wsg = (const float*)d_in[5];
  const float* wsu = (const float*)d_in[6];
  const float* wsd = (const float*)d_in[7];
  float* out = (float*)d_out;

  char* ws = (char*)d_ws;
  size_t o = 0;
  auto alloc = [&](size_t bytes) -> void* {
    void* p = ws + o;
    o += (bytes + 255) & ~(size_t)255;
    return p;
  };
  u16* xb   = (u16*)alloc((size_t)T_TOK * DMODEL * 2);
  u16* wbg  = (u16*)alloc((size_t)NEXP * DFF * DMODEL * 2);
  u16* wbu  = (u16*)alloc((size_t)NEXP * DFF * DMODEL * 2);
  u16* wbd  = (u16*)alloc((size_t)NEXP * DMODEL * DFF * 2);
  u16* wbsg = (u16*)alloc((size_t)DFFS * DMODEL * 2);
  u16* wbsu = (u16*)alloc((size_t)DFFS * DMODEL * 2);
  u16* wbsd = (u16*)alloc((size_t)DMODEL * DFFS * 2);
  u16* P1   = (u16*)alloc((size_t)NSLOT * DFF * 2);   // g buffers (reused shared)
  u16* P2   = (u16*)alloc((size_t)NSLOT * DFF * 2);   // u buffers
  u16* P3   = (u16*)alloc((size_t)NSLOT * DFF * 2);   // h buffers
  u16* yr   = (u16*)alloc((size_t)NSLOT * DMODEL * 2);
  float* tkw = (float*)alloc((size_t)T_TOK * 2 * 4);
  int* tki   = (int*)alloc((size_t)T_TOK * 2 * 4);
  int* pos   = (int*)alloc((size_t)T_TOK * 2 * 4);
  int* slot_tok = (int*)alloc((size_t)NSLOT * 4);
  int* counts   = (int*)alloc(64);
  int* offs     = (int*)alloc(64);
  int* cursor   = (int*)alloc(64);
  if (o > ws_size) {
    fprintf(stderr, "kernel_launch: ws too small: need %zu have %zu\n", o, ws_size);
    return;
  }

  // --- conversions fp32 -> bf16 ---
  {
    int n4x = T_TOK * DMODEL / 4;
    k_convert<<<(n4x + 255) / 256, 256, 0, stream>>>(x, xb, n4x);
    int n4w = NEXP * DFF * DMODEL / 4;
    k_convert<<<(n4w + 255) / 256, 256, 0, stream>>>(wg, wbg, n4w);
    k_convert<<<(n4w + 255) / 256, 256, 0, stream>>>(wu, wbu, n4w);
    k_convert<<<(n4w + 255) / 256, 256, 0, stream>>>(wd, wbd, n4w);
    int n4s = DFFS * DMODEL / 4;
    k_convert<<<(n4s + 255) / 256, 256, 0, stream>>>(wsg, wbsg, n4s);
    k_convert<<<(n4s + 255) / 256, 256, 0, stream>>>(wsu, wbsu, n4s);
    k_convert<<<(n4s + 255) / 256, 256, 0, stream>>>(wsd, wbsd, n4s);
  }

  // --- routing ---
  k_zero<<<1, 64, 0, stream>>>(counts);
  k_router<<<T_TOK, 64, 0, stream>>>(x, gw, tkw, tki, counts);
  k_scan<<<1, 64, 0, stream>>>(counts, offs, cursor);
  k_assign<<<(T_TOK + 255) / 256, 256, 0, stream>>>(tki, cursor, pos, slot_tok);

  size_t estride_gu = (size_t)DFF * DMODEL;
  size_t estride_d  = (size_t)DMODEL * DFF;

  // --- routed experts ---
  k_gemm<DMODEL, true, true, false><<<dim3(11, 64, 8), 256, 0, stream>>>(
      xb, wbg, estride_gu, P1, DFF, offs, counts, slot_tok, 0);
  k_gemm<DMODEL, true, true, false><<<dim3(11, 64, 8), 256, 0, stream>>>(
      xb, wbu, estride_gu, P2, DFF, offs, counts, slot_tok, 0);
  {
    int n8 = NSLOT * DFF / 8;
    k_silu_mul<<<(n8 + 255) / 256, 256, 0, stream>>>(P1, P2, P3, n8);
  }
  k_gemm<DFF, true, false, false><<<dim3(16, 64, 8), 256, 0, stream>>>(
      P3, wbd, estride_d, yr, DMODEL, offs, counts, nullptr, 0);

  // --- shared experts (reuse P1/P2/P3) ---
  k_gemm<DMODEL, false, false, false><<<dim3(22, 32, 1), 256, 0, stream>>>(
      xb, wbsg, 0, P1, DFFS, nullptr, nullptr, nullptr, T_TOK);
  k_gemm<DMODEL, false, false, false><<<dim3(22, 32, 1), 256, 0, stream>>>(
      xb, wbsu, 0, P2, DFFS, nullptr, nullptr, nullptr, T_TOK);
  {
    int n8 = T_TOK * DFFS / 8;
    k_silu_mul<<<(n8 + 255) / 256, 256, 0, stream>>>(P1, P2, P3, n8);
  }
  k_gemm<DFFS, false, false, true><<<dim3(16, 32, 1), 256, 0, stream>>>(
      P3, wbsd, 0, out, DMODEL, nullptr, nullptr, nullptr, T_TOK);

  // --- combine routed into output ---
  k_combine<<<T_TOK, 256, 0, stream>>>(out, yr, tkw, pos);
}

// Round 2
// 724.548 us; speedup vs baseline: 1.0808x; 1.0808x over previous
//
#include <hip/hip_runtime.h>
#include <stdint.h>
#include <stdio.h>

#define T_TOK 4096
#define DMODEL 2048
#define NEXP 8
#define DFF 1408
#define DFFS 2816
#define NSLOT 8192   // T_TOK * 2

typedef unsigned short u16;
typedef short s16x8 __attribute__((ext_vector_type(8)));
typedef __bf16 bf16x8 __attribute__((ext_vector_type(8)));
typedef float f32x4 __attribute__((ext_vector_type(4)));

__device__ __forceinline__ u16 f2bf(float f) {
  uint32_t u = __builtin_bit_cast(uint32_t, f);
  u += 0x7fffu + ((u >> 16) & 1u);
  return (u16)(u >> 16);
}
__device__ __forceinline__ float bf2f(u16 h) {
  uint32_t u = ((uint32_t)h) << 16;
  return __builtin_bit_cast(float, u);
}

// async global->LDS, 16B per lane; LDS dest is wave-uniform base + lane*16
__device__ __forceinline__ void gl16(const u16* g, u16* l) {
  __builtin_amdgcn_global_load_lds((const __attribute__((address_space(1))) void*)g,
                                   (__attribute__((address_space(3))) void*)l,
                                   16, 0, 0);
}

// ---------------- fp32 -> bf16 convert (8 elems/thread, 16B stores) ----------------
__global__ void k_convert(const float* __restrict__ in, u16* __restrict__ out, int n8) {
  int i = blockIdx.x * 256 + threadIdx.x;
  if (i >= n8) return;
  float4 a = ((const float4*)in)[2 * i];
  float4 b = ((const float4*)in)[2 * i + 1];
  s16x8 r;
  r[0] = (short)f2bf(a.x); r[1] = (short)f2bf(a.y);
  r[2] = (short)f2bf(a.z); r[3] = (short)f2bf(a.w);
  r[4] = (short)f2bf(b.x); r[5] = (short)f2bf(b.y);
  r[6] = (short)f2bf(b.z); r[7] = (short)f2bf(b.w);
  ((s16x8*)out)[i] = r;
}

// ---------------- zero counts ----------------
__global__ void k_zero(int* __restrict__ counts) {
  if (threadIdx.x < NEXP) counts[threadIdx.x] = 0;
}

// ---------------- router: one wave per token, float4 loads, 8-expert ILP ----------------
__global__ void k_router(const float* __restrict__ x, const float* __restrict__ gw,
                         float* __restrict__ tkw, int* __restrict__ tki,
                         int* __restrict__ counts) {
  int t = blockIdx.x;
  int lane = threadIdx.x;
  const float4* xr = (const float4*)(x + (size_t)t * DMODEL);
  const float4* gr = (const float4*)gw;
  double acc[NEXP];
#pragma unroll
  for (int e = 0; e < NEXP; ++e) acc[e] = 0.0;
#pragma unroll
  for (int it = 0; it < DMODEL / 4 / 64; ++it) {   // 8 iters
    int idx = it * 64 + lane;
    float4 xv = xr[idx];
#pragma unroll
    for (int e = 0; e < NEXP; ++e) {
      float4 gv = gr[e * (DMODEL / 4) + idx];
      acc[e] += (double)xv.x * gv.x + (double)xv.y * gv.y +
                (double)xv.z * gv.z + (double)xv.w * gv.w;
    }
  }
#pragma unroll
  for (int e = 0; e < NEXP; ++e) {
#pragma unroll
    for (int off = 32; off; off >>= 1) acc[e] += __shfl_down(acc[e], off, 64);
  }
  if (lane == 0) {
    int i0 = 0; double v0 = acc[0];
    for (int e = 1; e < NEXP; ++e) if (acc[e] > v0) { v0 = acc[e]; i0 = e; }
    int i1 = -1; double v1 = -1e300;
    for (int e = 0; e < NEXP; ++e) if (e != i0 && acc[e] > v1) { v1 = acc[e]; i1 = e; }
    double r = exp(v1 - v0);              // <= 1
    float w0 = (float)(1.0 / (1.0 + r));
    float w1 = 1.0f - w0;
    tkw[2 * t] = w0; tkw[2 * t + 1] = w1;
    tki[2 * t] = i0; tki[2 * t + 1] = i1;
    atomicAdd(&counts[i0], 1);
    atomicAdd(&counts[i1], 1);
  }
}

// ---------------- exclusive scan over 8 experts ----------------
__global__ void k_scan(const int* __restrict__ counts, int* __restrict__ offs,
                       int* __restrict__ cursor) {
  if (threadIdx.x == 0) {
    int s = 0;
    for (int e = 0; e < NEXP; ++e) { offs[e] = s; cursor[e] = s; s += counts[e]; }
    offs[NEXP] = s;
  }
}

// ---------------- assign compacted slots ----------------
__global__ void k_assign(const int* __restrict__ tki, int* __restrict__ cursor,
                         int* __restrict__ pos, int* __restrict__ slot_tok) {
  int t = blockIdx.x * 256 + threadIdx.x;
  if (t >= T_TOK) return;
#pragma unroll
  for (int k = 0; k < 2; ++k) {
    int e = tki[2 * t + k];
    int p = atomicAdd(&cursor[e], 1);
    pos[2 * t + k] = p;
    slot_tok[p] = t;
  }
}

// ---------------- NT bf16 GEMM: C[M,N] = A[M,K] * B[N,K]^T ----------------
// m97 structure: 128x128 tile, BK=64, 4 waves (2x2 of 64x64), 16x16x32 MFMA,
// global_load_lds width-16 staging into LINEAR LDS, 2-barrier loop.
// Fused dual-B: n-blocks with n0 >= nsplit use B2/C2 at col n0-nsplit
// (gate+up in one dispatch). Output row stride = nsplit.
// EPI: 0 = bf16 store to Csel; 2 = f32 store to OF.
template <int KD, bool PEREXP, bool GATHER, int EPI>
__launch_bounds__(256, 2)
__global__ void k_gemm(const u16* __restrict__ A,
                       const u16* __restrict__ B1, const u16* __restrict__ B2,
                       size_t b_estride,
                       u16* __restrict__ C1, u16* __restrict__ C2,
                       float* __restrict__ OF, int nsplit,
                       const int* __restrict__ offs, const int* __restrict__ counts,
                       const int* __restrict__ slot_tok, int m_total) {
  constexpr int BM = 128, BN = 128, BK = 64;
  __shared__ __attribute__((aligned(16))) u16 As[BM * BK];
  __shared__ __attribute__((aligned(16))) u16 Bs[BN * BK];

  int e, base, cnt;
  if constexpr (PEREXP) {
    e = blockIdx.z; base = offs[e]; cnt = counts[e];
  } else {
    e = 0; base = 0; cnt = m_total;
  }
  int m0 = blockIdx.y * BM;
  if (m0 >= cnt) return;
  int n0 = blockIdx.x * BN;

  const u16* Bsel = B1;
  u16* Csel = C1;
  int ncol = n0;
  if (n0 >= nsplit) { Bsel = B2; Csel = C2; ncol = n0 - nsplit; }

  int tid = threadIdx.x;
  int lane = tid & 63, wv = tid >> 6;
  int l8 = lane >> 3, l7 = lane & 7;

  // staging pointers: wave wv covers rows [wv*32, wv*32+32), 4 chunks of 8 rows
  const u16* ap[4];
  const u16* bp[4];
#pragma unroll
  for (int c = 0; c < 4; ++c) {
    int r = m0 + wv * 32 + c * 8 + l8;
    int rc = r < cnt ? r : cnt - 1;
    int ga;
    if constexpr (GATHER) ga = slot_tok[base + rc];
    else                  ga = base + rc;
    ap[c] = A + (size_t)ga * KD + l7 * 8;
    bp[c] = Bsel + b_estride * (size_t)e +
            (size_t)(ncol + wv * 32 + c * 8 + l8) * KD + l7 * 8;
  }

  int fr = lane & 15, fq = lane >> 4;
  int wr = (wv >> 1) * 64, wc = (wv & 1) * 64;

  f32x4 zero = {0.f, 0.f, 0.f, 0.f};
  f32x4 acc[4][4];
#pragma unroll
  for (int i = 0; i < 4; ++i)
#pragma unroll
    for (int j = 0; j < 4; ++j) acc[i][j] = zero;

  for (int k0 = 0; k0 < KD; k0 += BK) {
#pragma unroll
    for (int c = 0; c < 4; ++c) gl16(ap[c] + k0, &As[(wv * 32 + c * 8) * BK]);
#pragma unroll
    for (int c = 0; c < 4; ++c) gl16(bp[c] + k0, &Bs[(wv * 32 + c * 8) * BK]);
    __syncthreads();   // vmcnt(0) drained by compiler before barrier
#pragma unroll
    for (int ks = 0; ks < 2; ++ks) {
      bf16x8 af[4], bfr[4];
#pragma unroll
      for (int i = 0; i < 4; ++i) {
        af[i]  = *(const bf16x8*)&As[(wr + i * 16 + fr) * BK + ks * 32 + fq * 8];
        bfr[i] = *(const bf16x8*)&Bs[(wc + i * 16 + fr) * BK + ks * 32 + fq * 8];
      }
#pragma unroll
      for (int i = 0; i < 4; ++i)
#pragma unroll
        for (int j = 0; j < 4; ++j)
          acc[i][j] = __builtin_amdgcn_mfma_f32_16x16x32_bf16(af[i], bfr[j], acc[i][j], 0, 0, 0);
    }
    __syncthreads();   // all reads done before next stage overwrites
  }

#pragma unroll
  for (int i = 0; i < 4; ++i) {
    int rl = wr + i * 16 + fq * 4;
#pragma unroll
    for (int r = 0; r < 4; ++r) {
      int m = m0 + rl + r;
      if (m >= cnt) continue;
      size_t rowoff = (size_t)(base + m) * (size_t)nsplit;
#pragma unroll
      for (int j = 0; j < 4; ++j) {
        int col = ncol + wc + j * 16 + fr;
        if constexpr (EPI == 2) OF[rowoff + col] = acc[i][j][r];
        else                    Csel[rowoff + col] = f2bf(acc[i][j][r]);
      }
    }
  }
}

// ---------------- h = silu(g) * u, 8 elems/thread (in-place capable) ----------------
__global__ void k_silu_mul(const u16* __restrict__ g, const u16* __restrict__ u,
                           u16* __restrict__ h, int n8) {
  int i = blockIdx.x * 256 + threadIdx.x;
  if (i >= n8) return;
  s16x8 gv = ((const s16x8*)g)[i];
  s16x8 uv = ((const s16x8*)u)[i];
  s16x8 hv;
#pragma unroll
  for (int j = 0; j < 8; ++j) {
    float gf = bf2f((u16)gv[j]);
    float uf = bf2f((u16)uv[j]);
    float s = gf / (1.f + __expf(-gf));
    hv[j] = (short)f2bf(s * uf);
  }
  ((s16x8*)h)[i] = hv;
}

// ---------------- y[t] += w0*yr[pos0] + w1*yr[pos1] ----------------
__global__ void k_combine(float* __restrict__ y, const u16* __restrict__ yr,
                          const float* __restrict__ tkw, const int* __restrict__ pos) {
  int t = blockIdx.x;
  int i = threadIdx.x;
  float w0 = tkw[2 * t], w1 = tkw[2 * t + 1];
  size_t p0 = (size_t)pos[2 * t] * DMODEL, p1 = (size_t)pos[2 * t + 1] * DMODEL;
  int d0 = i * 8;
  s16x8 a = *(const s16x8*)(yr + p0 + d0);
  s16x8 b = *(const s16x8*)(yr + p1 + d0);
  float* yo = y + (size_t)t * DMODEL + d0;
#pragma unroll
  for (int j = 0; j < 8; ++j)
    yo[j] += w0 * bf2f((u16)a[j]) + w1 * bf2f((u16)b[j]);
}

extern "C" void kernel_launch(void* const* d_in, const int* in_sizes, int n_in,
                              void* d_out, int out_size, void* d_ws, size_t ws_size,
                              hipStream_t stream) {
  const float* x   = (const float*)d_in[0];
  const float* gw  = (const float*)d_in[1];
  const float* wg  = (const float*)d_in[2];
  const float* wu  = (const float*)d_in[3];
  const float* wd  = (const float*)d_in[4];
  const float* wsg = (const float*)d_in[5];
  const float* wsu = (const float*)d_in[6];
  const float* wsd = (const float*)d_in[7];
  float* out = (float*)d_out;

  char* ws = (char*)d_ws;
  size_t o = 0;
  auto alloc = [&](size_t bytes) -> void* {
    void* p = ws + o;
    o += (bytes + 255) & ~(size_t)255;
    return p;
  };
  u16* xb   = (u16*)alloc((size_t)T_TOK * DMODEL * 2);
  u16* wbg  = (u16*)alloc((size_t)NEXP * DFF * DMODEL * 2);
  u16* wbu  = (u16*)alloc((size_t)NEXP * DFF * DMODEL * 2);
  u16* wbd  = (u16*)alloc((size_t)NEXP * DMODEL * DFF * 2);
  u16* wbsg = (u16*)alloc((size_t)DFFS * DMODEL * 2);
  u16* wbsu = (u16*)alloc((size_t)DFFS * DMODEL * 2);
  u16* wbsd = (u16*)alloc((size_t)DMODEL * DFFS * 2);
  u16* P1   = (u16*)alloc((size_t)NSLOT * DFF * 2);   // == T_TOK*DFFS*2
  u16* P2   = (u16*)alloc((size_t)NSLOT * DFF * 2);
  u16* yr   = (u16*)alloc((size_t)NSLOT * DMODEL * 2);
  float* tkw = (float*)alloc((size_t)T_TOK * 2 * 4);
  int* tki   = (int*)alloc((size_t)T_TOK * 2 * 4);
  int* pos   = (int*)alloc((size_t)T_TOK * 2 * 4);
  int* slot_tok = (int*)alloc((size_t)NSLOT * 4);
  int* counts   = (int*)alloc(64);
  int* offs     = (int*)alloc(64);
  int* cursor   = (int*)alloc(64);
  if (o > ws_size) {
    fprintf(stderr, "kernel_launch: ws too small: need %zu have %zu\n", o, ws_size);
    return;
  }

  // --- conversions fp32 -> bf16 (8 elems/thread) ---
  {
    int n8x = T_TOK * DMODEL / 8;
    k_convert<<<(n8x + 255) / 256, 256, 0, stream>>>(x, xb, n8x);
    int n8w = NEXP * DFF * DMODEL / 8;
    k_convert<<<(n8w + 255) / 256, 256, 0, stream>>>(wg, wbg, n8w);
    k_convert<<<(n8w + 255) / 256, 256, 0, stream>>>(wu, wbu, n8w);
    k_convert<<<(n8w + 255) / 256, 256, 0, stream>>>(wd, wbd, n8w);
    int n8s = DFFS * DMODEL / 8;
    k_convert<<<(n8s + 255) / 256, 256, 0, stream>>>(wsg, wbsg, n8s);
    k_convert<<<(n8s + 255) / 256, 256, 0, stream>>>(wsu, wbsu, n8s);
    k_convert<<<(n8s + 255) / 256, 256, 0, stream>>>(wsd, wbsd, n8s);
  }

  // --- routing ---
  k_zero<<<1, 64, 0, stream>>>(counts);
  k_router<<<T_TOK, 64, 0, stream>>>(x, gw, tkw, tki, counts);
  k_scan<<<1, 64, 0, stream>>>(counts, offs, cursor);
  k_assign<<<(T_TOK + 255) / 256, 256, 0, stream>>>(tki, cursor, pos, slot_tok);

  size_t estride_gu = (size_t)DFF * DMODEL;
  size_t estride_d  = (size_t)DMODEL * DFF;

  // --- routed experts: fused gate+up (N = 2*1408 -> 22 n-blocks), cnt<=2560 ---
  k_gemm<DMODEL, true, true, 0><<<dim3(22, 20, 8), 256, 0, stream>>>(
      xb, wbg, wbu, estride_gu, P1, P2, nullptr, DFF, offs, counts, slot_tok, 0);
  {
    int n8 = NSLOT * DFF / 8;
    k_silu_mul<<<(n8 + 255) / 256, 256, 0, stream>>>(P1, P2, P1, n8);  // in-place
  }
  k_gemm<DFF, true, false, 0><<<dim3(16, 20, 8), 256, 0, stream>>>(
      P1, wbd, wbd, estride_d, yr, yr, nullptr, DMODEL, offs, counts, nullptr, 0);

  // --- shared experts: fused gate+up (N = 2*2816 -> 44 n-blocks) ---
  k_gemm<DMODEL, false, false, 0><<<dim3(44, 32, 1), 256, 0, stream>>>(
      xb, wbsg, wbsu, 0, P1, P2, nullptr, DFFS, nullptr, nullptr, nullptr, T_TOK);
  {
    int n8 = T_TOK * DFFS / 8;
    k_silu_mul<<<(n8 + 255) / 256, 256, 0, stream>>>(P1, P2, P1, n8);  // in-place
  }
  k_gemm<DFFS, false, false, 2><<<dim3(16, 32, 1), 256, 0, stream>>>(
      P1, wbsd, wbsd, 0, yr, yr, out, DMODEL, nullptr, nullptr, nullptr, T_TOK);

  // --- combine routed into output ---
  k_combine<<<T_TOK, 256, 0, stream>>>(out, yr, tkw, pos);
}

// Round 3
// 724.130 us; speedup vs baseline: 1.0814x; 1.0006x over previous
//
#include <hip/hip_runtime.h>
#include <stdint.h>
#include <stdio.h>

#define T_TOK 4096
#define DMODEL 2048
#define NEXP 8
#define DFF 1408
#define DFFS 2816
#define NSLOT 8192   // T_TOK * 2

typedef unsigned short u16;
typedef short s16x8 __attribute__((ext_vector_type(8)));
typedef __bf16 bf16x8 __attribute__((ext_vector_type(8)));
typedef float f32x4 __attribute__((ext_vector_type(4)));

__device__ __forceinline__ u16 f2bf(float f) {
  uint32_t u = __builtin_bit_cast(uint32_t, f);
  u += 0x7fffu + ((u >> 16) & 1u);
  return (u16)(u >> 16);
}
__device__ __forceinline__ float bf2f(u16 h) {
  uint32_t u = ((uint32_t)h) << 16;
  return __builtin_bit_cast(float, u);
}

// async global->LDS, 16B per lane; LDS dest = wave-uniform base + lane*16
__device__ __forceinline__ void gl16(const u16* g, u16* l) {
  __builtin_amdgcn_global_load_lds((const __attribute__((address_space(1))) void*)g,
                                   (__attribute__((address_space(3))) void*)l,
                                   16, 0, 0);
}

// ---------------- fp32 -> bf16 convert (8 elems/thread) ----------------
__global__ void k_convert(const float* __restrict__ in, u16* __restrict__ out, int n8) {
  int i = blockIdx.x * 256 + threadIdx.x;
  if (i >= n8) return;
  float4 a = ((const float4*)in)[2 * i];
  float4 b = ((const float4*)in)[2 * i + 1];
  s16x8 r;
  r[0] = (short)f2bf(a.x); r[1] = (short)f2bf(a.y);
  r[2] = (short)f2bf(a.z); r[3] = (short)f2bf(a.w);
  r[4] = (short)f2bf(b.x); r[5] = (short)f2bf(b.y);
  r[6] = (short)f2bf(b.z); r[7] = (short)f2bf(b.w);
  ((s16x8*)out)[i] = r;
}

__global__ void k_zero(int* __restrict__ counts) {
  if (threadIdx.x < NEXP) counts[threadIdx.x] = 0;
}

// ---------------- router: one wave per token, float4 loads, 8-expert ILP ----------------
__global__ void k_router(const float* __restrict__ x, const float* __restrict__ gw,
                         float* __restrict__ tkw, int* __restrict__ tki,
                         int* __restrict__ counts) {
  int t = blockIdx.x;
  int lane = threadIdx.x;
  const float4* xr = (const float4*)(x + (size_t)t * DMODEL);
  const float4* gr = (const float4*)gw;
  double acc[NEXP];
#pragma unroll
  for (int e = 0; e < NEXP; ++e) acc[e] = 0.0;
#pragma unroll
  for (int it = 0; it < DMODEL / 4 / 64; ++it) {   // 8 iters
    int idx = it * 64 + lane;
    float4 xv = xr[idx];
#pragma unroll
    for (int e = 0; e < NEXP; ++e) {
      float4 gv = gr[e * (DMODEL / 4) + idx];
      acc[e] += (double)xv.x * gv.x + (double)xv.y * gv.y +
                (double)xv.z * gv.z + (double)xv.w * gv.w;
    }
  }
#pragma unroll
  for (int e = 0; e < NEXP; ++e) {
#pragma unroll
    for (int off = 32; off; off >>= 1) acc[e] += __shfl_down(acc[e], off, 64);
  }
  if (lane == 0) {
    int i0 = 0; double v0 = acc[0];
    for (int e = 1; e < NEXP; ++e) if (acc[e] > v0) { v0 = acc[e]; i0 = e; }
    int i1 = -1; double v1 = -1e300;
    for (int e = 0; e < NEXP; ++e) if (e != i0 && acc[e] > v1) { v1 = acc[e]; i1 = e; }
    double r = exp(v1 - v0);
    float w0 = (float)(1.0 / (1.0 + r));
    float w1 = 1.0f - w0;
    tkw[2 * t] = w0; tkw[2 * t + 1] = w1;
    tki[2 * t] = i0; tki[2 * t + 1] = i1;
    atomicAdd(&counts[i0], 1);
    atomicAdd(&counts[i1], 1);
  }
}

__global__ void k_scan(const int* __restrict__ counts, int* __restrict__ offs,
                       int* __restrict__ cursor) {
  if (threadIdx.x == 0) {
    int s = 0;
    for (int e = 0; e < NEXP; ++e) { offs[e] = s; cursor[e] = s; s += counts[e]; }
    offs[NEXP] = s;
  }
}

__global__ void k_assign(const int* __restrict__ tki, int* __restrict__ cursor,
                         int* __restrict__ pos, int* __restrict__ slot_tok) {
  int t = blockIdx.x * 256 + threadIdx.x;
  if (t >= T_TOK) return;
#pragma unroll
  for (int k = 0; k < 2; ++k) {
    int e = tki[2 * t + k];
    int p = atomicAdd(&cursor[e], 1);
    pos[2 * t + k] = p;
    slot_tok[p] = t;
  }
}

// ---------------- 256x256 8-phase NT bf16 GEMM (T2+T3+T4+T5) ----------------
// C[M,N] = A[M,K] * B[N,K]^T. 512 threads = 8 waves (2M x 4N). BK=64.
// LDS: 2 dbuf x (A 256x64 + B 256x64) bf16 = 128 KiB, XOR-swizzled slots.
// Staging: global_load_lds w16, pre-swizzled global source (slot ^= row&7).
// Schedule per K-tile: top {issue A-half0(t+1); vmcnt(2); barrier} then 4 phases
// {ds_read quad; issue 1 half-tile(t+1); barrier; lgkmcnt(0); 16 MFMA (setprio)}.
// Dual-B fusion: per-ROW / per-COL select of B1/B2 at the nsplit boundary.
template <int KD, bool PEREXP, bool GATHER, int EPI>
__launch_bounds__(512, 2)
__global__ void k_gemm8(const u16* __restrict__ A,
                        const u16* __restrict__ B1, const u16* __restrict__ B2,
                        size_t b_estride,
                        u16* __restrict__ C1, u16* __restrict__ C2,
                        float* __restrict__ OF, int nsplit,
                        const int* __restrict__ offs, const int* __restrict__ counts,
                        const int* __restrict__ slot_tok, int m_total) {
  constexpr int NT = KD / 64;
  __shared__ __attribute__((aligned(16))) u16 lds[2 * 32768];  // 128 KiB

  int e, base, cnt;
  if constexpr (PEREXP) { e = blockIdx.z; base = offs[e]; cnt = counts[e]; }
  else { e = 0; base = 0; cnt = m_total; }
  int m0 = blockIdx.y * 256;
  if (m0 >= cnt) return;
  int n0 = blockIdx.x * 256;

  int tid = threadIdx.x;
  int lane = tid & 63, wv = tid >> 6;
  int wm = wv >> 2, wn = wv & 3;
  int fr = lane & 15, fq = lane >> 4;

  // --- staging source pointers: 4 A-slabs + 4 B-slabs (64 rows each)
  int srow = tid >> 3;                     // 0..63
  int sslot = (tid & 7) ^ (srow & 7);      // T2 pre-swizzle (involution)
  const u16* ap[4]; const u16* bp[4];
#pragma unroll
  for (int hs = 0; hs < 4; ++hs) {
    int r = hs * 64 + srow;                // tile row 0..255
    int ra = m0 + r; ra = ra < cnt ? ra : cnt - 1;
    int ga;
    if constexpr (GATHER) ga = slot_tok[base + ra];
    else                  ga = base + ra;
    ap[hs] = A + (size_t)ga * KD + sslot * 8;
    int nc = n0 + r;
    const u16* bb = (nc >= nsplit) ? (B2 + (size_t)(nc - nsplit) * KD)
                                   : (B1 + (size_t)nc * KD);
    bp[hs] = bb + b_estride * (size_t)e + sslot * 8;
  }

#define STAGE(Tn, hs, buf, kt) \
  gl16(((Tn) ? bp[hs] : ap[hs]) + (size_t)(kt) * 64, \
       lds + ((buf) * 32768 + (Tn) * 16384 + (hs) * 4096 + wv * 512))

  // --- read bases (u16 elems); swizzled slot is lane-constant per ks
  int sKs0 = ((0 + fq) ^ (fr & 7)) * 8;
  int sKs1 = ((4 + fq) ^ (fr & 7)) * 8;
  int aBase = wm * 8192 + fr * 64;                                   // + i*1024
  int bBase = 16384 + (wn >> 1) * 8192 + ((wn & 1) * 64 + fr) * 64;  // + j*1024

  f32x4 acc[8][4];
#pragma unroll
  for (int i = 0; i < 8; ++i)
#pragma unroll
    for (int j = 0; j < 4; ++j) acc[i][j] = (f32x4){0.f, 0.f, 0.f, 0.f};

  // prologue: stage tile 0 fully (8 calls)
#pragma unroll
  for (int hs = 0; hs < 4; ++hs) STAGE(0, hs, 0, 0);
#pragma unroll
  for (int hs = 0; hs < 4; ++hs) STAGE(1, hs, 0, 0);

  bf16x8 af[4][2];
  for (int t = 0; t < NT; ++t) {
    int buf = t & 1, nbuf = buf ^ 1;
    bool hn = (t + 1) < NT;
    if (hn) { STAGE(0, 0, nbuf, t + 1); STAGE(0, 1, nbuf, t + 1); }
    if (hn) asm volatile("s_waitcnt vmcnt(2)" ::: "memory");
    else    asm volatile("s_waitcnt vmcnt(0)" ::: "memory");
    __builtin_amdgcn_s_barrier();
    __builtin_amdgcn_sched_barrier(0);

    const u16* lbuf = lds + buf * 32768;
#pragma unroll
    for (int p = 0; p < 4; ++p) {
      const int mq = p >> 1, nq = p & 1;
      if (nq == 0) {
#pragma unroll
        for (int il = 0; il < 4; ++il) {
          int i = mq * 4 + il;
          af[il][0] = *(const bf16x8*)(lbuf + aBase + i * 1024 + sKs0);
          af[il][1] = *(const bf16x8*)(lbuf + aBase + i * 1024 + sKs1);
        }
      }
      bf16x8 bf_[2][2];
#pragma unroll
      for (int jl = 0; jl < 2; ++jl) {
        int j = nq * 2 + jl;
        bf_[jl][0] = *(const bf16x8*)(lbuf + bBase + j * 1024 + sKs0);
        bf_[jl][1] = *(const bf16x8*)(lbuf + bBase + j * 1024 + sKs1);
      }
      if (hn) {
        if (p == 0)      { STAGE(0, 2, nbuf, t + 1); STAGE(0, 3, nbuf, t + 1); }
        else if (p == 1) { STAGE(1, 0, nbuf, t + 1); STAGE(1, 1, nbuf, t + 1); }
        else if (p == 2) { STAGE(1, 2, nbuf, t + 1); STAGE(1, 3, nbuf, t + 1); }
      }
      __builtin_amdgcn_s_barrier();
      asm volatile("s_waitcnt lgkmcnt(0)" ::: "memory");
      __builtin_amdgcn_sched_barrier(0);
      __builtin_amdgcn_s_setprio(1);
#pragma unroll
      for (int il = 0; il < 4; ++il)
#pragma unroll
        for (int jl = 0; jl < 2; ++jl) {
          int i = mq * 4 + il, j = nq * 2 + jl;
          acc[i][j] = __builtin_amdgcn_mfma_f32_16x16x32_bf16(af[il][0], bf_[jl][0], acc[i][j], 0, 0, 0);
          acc[i][j] = __builtin_amdgcn_mfma_f32_16x16x32_bf16(af[il][1], bf_[jl][1], acc[i][j], 0, 0, 0);
        }
      __builtin_amdgcn_s_setprio(0);
      __builtin_amdgcn_sched_barrier(0);
      __builtin_amdgcn_s_barrier();
    }
  }
#undef STAGE

  // --- epilogue ---
#pragma unroll
  for (int i = 0; i < 8; ++i) {
    int row_t = wm * 128 + i * 16 + fq * 4;
#pragma unroll
    for (int r = 0; r < 4; ++r) {
      int m = m0 + row_t + r;
      if (m >= cnt) continue;
      size_t rowoff = (size_t)(base + m) * (size_t)nsplit;
#pragma unroll
      for (int j = 0; j < 4; ++j) {
        int col_t = n0 + wn * 64 + j * 16 + fr;
        float v = acc[i][j][r];
        if constexpr (EPI == 2) {
          OF[rowoff + col_t] = v;
        } else {
          if (col_t >= nsplit) C2[rowoff + col_t - nsplit] = f2bf(v);
          else                 C1[rowoff + col_t] = f2bf(v);
        }
      }
    }
  }
}

// ---------------- h = silu(g) * u ----------------
__global__ void k_silu_mul(const u16* __restrict__ g, const u16* __restrict__ u,
                           u16* __restrict__ h, int n8) {
  int i = blockIdx.x * 256 + threadIdx.x;
  if (i >= n8) return;
  s16x8 gv = ((const s16x8*)g)[i];
  s16x8 uv = ((const s16x8*)u)[i];
  s16x8 hv;
#pragma unroll
  for (int j = 0; j < 8; ++j) {
    float gf = bf2f((u16)gv[j]);
    float uf = bf2f((u16)uv[j]);
    float s = gf / (1.f + __expf(-gf));
    hv[j] = (short)f2bf(s * uf);
  }
  ((s16x8*)h)[i] = hv;
}

// ---------------- y[t] += w0*yr[pos0] + w1*yr[pos1] ----------------
__global__ void k_combine(float* __restrict__ y, const u16* __restrict__ yr,
                          const float* __restrict__ tkw, const int* __restrict__ pos) {
  int t = blockIdx.x;
  int i = threadIdx.x;
  float w0 = tkw[2 * t], w1 = tkw[2 * t + 1];
  size_t p0 = (size_t)pos[2 * t] * DMODEL, p1 = (size_t)pos[2 * t + 1] * DMODEL;
  int d0 = i * 8;
  s16x8 a = *(const s16x8*)(yr + p0 + d0);
  s16x8 b = *(const s16x8*)(yr + p1 + d0);
  float* yo = y + (size_t)t * DMODEL + d0;
#pragma unroll
  for (int j = 0; j < 8; ++j)
    yo[j] += w0 * bf2f((u16)a[j]) + w1 * bf2f((u16)b[j]);
}

extern "C" void kernel_launch(void* const* d_in, const int* in_sizes, int n_in,
                              void* d_out, int out_size, void* d_ws, size_t ws_size,
                              hipStream_t stream) {
  const float* x   = (const float*)d_in[0];
  const float* gw  = (const float*)d_in[1];
  const float* wg  = (const float*)d_in[2];
  const float* wu  = (const float*)d_in[3];
  const float* wd  = (const float*)d_in[4];
  const float* wsg = (const float*)d_in[5];
  const float* wsu = (const float*)d_in[6];
  const float* wsd = (const float*)d_in[7];
  float* out = (float*)d_out;

  char* ws = (char*)d_ws;
  size_t o = 0;
  auto alloc = [&](size_t bytes) -> void* {
    void* p = ws + o;
    o += (bytes + 255) & ~(size_t)255;
    return p;
  };
  u16* xb   = (u16*)alloc((size_t)T_TOK * DMODEL * 2);
  u16* wbg  = (u16*)alloc((size_t)NEXP * DFF * DMODEL * 2);
  u16* wbu  = (u16*)alloc((size_t)NEXP * DFF * DMODEL * 2);
  u16* wbd  = (u16*)alloc((size_t)NEXP * DMODEL * DFF * 2);
  u16* wbsg = (u16*)alloc((size_t)DFFS * DMODEL * 2);
  u16* wbsu = (u16*)alloc((size_t)DFFS * DMODEL * 2);
  u16* wbsd = (u16*)alloc((size_t)DMODEL * DFFS * 2);
  u16* P1   = (u16*)alloc((size_t)NSLOT * DFF * 2);   // == T_TOK*DFFS*2
  u16* P2   = (u16*)alloc((size_t)NSLOT * DFF * 2);
  u16* yr   = (u16*)alloc((size_t)NSLOT * DMODEL * 2);
  float* tkw = (float*)alloc((size_t)T_TOK * 2 * 4);
  int* tki   = (int*)alloc((size_t)T_TOK * 2 * 4);
  int* pos   = (int*)alloc((size_t)T_TOK * 2 * 4);
  int* slot_tok = (int*)alloc((size_t)NSLOT * 4);
  int* counts   = (int*)alloc(64);
  int* offs     = (int*)alloc(64);
  int* cursor   = (int*)alloc(64);
  if (o > ws_size) {
    fprintf(stderr, "kernel_launch: ws too small: need %zu have %zu\n", o, ws_size);
    return;
  }

  // --- conversions fp32 -> bf16 ---
  {
    int n8x = T_TOK * DMODEL / 8;
    k_convert<<<(n8x + 255) / 256, 256, 0, stream>>>(x, xb, n8x);
    int n8w = NEXP * DFF * DMODEL / 8;
    k_convert<<<(n8w + 255) / 256, 256, 0, stream>>>(wg, wbg, n8w);
    k_convert<<<(n8w + 255) / 256, 256, 0, stream>>>(wu, wbu, n8w);
    k_convert<<<(n8w + 255) / 256, 256, 0, stream>>>(wd, wbd, n8w);
    int n8s = DFFS * DMODEL / 8;
    k_convert<<<(n8s + 255) / 256, 256, 0, stream>>>(wsg, wbsg, n8s);
    k_convert<<<(n8s + 255) / 256, 256, 0, stream>>>(wsu, wbsu, n8s);
    k_convert<<<(n8s + 255) / 256, 256, 0, stream>>>(wsd, wbsd, n8s);
  }

  // --- routing ---
  k_zero<<<1, 64, 0, stream>>>(counts);
  k_router<<<T_TOK, 64, 0, stream>>>(x, gw, tkw, tki, counts);
  k_scan<<<1, 64, 0, stream>>>(counts, offs, cursor);
  k_assign<<<(T_TOK + 255) / 256, 256, 0, stream>>>(tki, cursor, pos, slot_tok);

  size_t estride_gu = (size_t)DFF * DMODEL;
  size_t estride_d  = (size_t)DMODEL * DFF;

  // --- routed experts: fused gate+up (N span = 2816 = 11 n-blocks) ---
  k_gemm8<DMODEL, true, true, 0><<<dim3(11, 16, 8), 512, 0, stream>>>(
      xb, wbg, wbu, estride_gu, P1, P2, nullptr, DFF, offs, counts, slot_tok, 0);
  {
    int n8 = NSLOT * DFF / 8;
    k_silu_mul<<<(n8 + 255) / 256, 256, 0, stream>>>(P1, P2, P1, n8);  // in-place
  }
  k_gemm8<DFF, true, false, 0><<<dim3(8, 16, 8), 512, 0, stream>>>(
      P1, wbd, wbd, estride_d, yr, yr, nullptr, DMODEL, offs, counts, nullptr, 0);

  // --- shared experts: fused gate+up (N span = 5632 = 22 n-blocks) ---
  k_gemm8<DMODEL, false, false, 0><<<dim3(22, 16, 1), 512, 0, stream>>>(
      xb, wbsg, wbsu, 0, P1, P2, nullptr, DFFS, nullptr, nullptr, nullptr, T_TOK);
  {
    int n8 = T_TOK * DFFS / 8;
    k_silu_mul<<<(n8 + 255) / 256, 256, 0, stream>>>(P1, P2, P1, n8);  // in-place
  }
  k_gemm8<DFFS, false, false, 2><<<dim3(8, 16, 1), 512, 0, stream>>>(
      P1, wbsd, wbsd, 0, yr, yr, out, DMODEL, nullptr, nullptr, nullptr, T_TOK);

  // --- combine routed into output ---
  k_combine<<<T_TOK, 256, 0, stream>>>(out, yr, tkw, pos);
}

// Round 4
// 681.075 us; speedup vs baseline: 1.1498x; 1.0632x over previous
//
#include <hip/hip_runtime.h>
#include <stdint.h>
#include <stdio.h>

#define T_TOK 4096
#define DMODEL 2048
#define NEXP 8
#define DFF 1408
#define DFFS 2816
#define NSLOT 8192   // T_TOK * 2

typedef unsigned short u16;
typedef short s16x8 __attribute__((ext_vector_type(8)));
typedef __bf16 bf16x8 __attribute__((ext_vector_type(8)));
typedef float f32x4 __attribute__((ext_vector_type(4)));

__device__ __forceinline__ u16 f2bf(float f) {
  uint32_t u = __builtin_bit_cast(uint32_t, f);
  u += 0x7fffu + ((u >> 16) & 1u);
  return (u16)(u >> 16);
}
__device__ __forceinline__ float bf2f(u16 h) {
  uint32_t u = ((uint32_t)h) << 16;
  return __builtin_bit_cast(float, u);
}

// async global->LDS, 16B per lane; LDS dest = wave-uniform base + lane*16
__device__ __forceinline__ void gl16(const u16* g, u16* l) {
  __builtin_amdgcn_global_load_lds((const __attribute__((address_space(1))) void*)g,
                                   (__attribute__((address_space(3))) void*)l,
                                   16, 0, 0);
}

#define BARRIER() asm volatile("s_barrier" ::: "memory")

// ---------------- fp32 -> bf16 convert (8 elems/thread) ----------------
__global__ void k_convert(const float* __restrict__ in, u16* __restrict__ out, int n8) {
  int i = blockIdx.x * 256 + threadIdx.x;
  if (i >= n8) return;
  float4 a = ((const float4*)in)[2 * i];
  float4 b = ((const float4*)in)[2 * i + 1];
  s16x8 r;
  r[0] = (short)f2bf(a.x); r[1] = (short)f2bf(a.y);
  r[2] = (short)f2bf(a.z); r[3] = (short)f2bf(a.w);
  r[4] = (short)f2bf(b.x); r[5] = (short)f2bf(b.y);
  r[6] = (short)f2bf(b.z); r[7] = (short)f2bf(b.w);
  ((s16x8*)out)[i] = r;
}

__global__ void k_zero(int* __restrict__ counts) {
  if (threadIdx.x < NEXP) counts[threadIdx.x] = 0;
}

// ---------------- router: one wave per token, float4 loads, 8-expert ILP ----------------
__global__ void k_router(const float* __restrict__ x, const float* __restrict__ gw,
                         float* __restrict__ tkw, int* __restrict__ tki,
                         int* __restrict__ counts) {
  int t = blockIdx.x;
  int lane = threadIdx.x;
  const float4* xr = (const float4*)(x + (size_t)t * DMODEL);
  const float4* gr = (const float4*)gw;
  double acc[NEXP];
#pragma unroll
  for (int e = 0; e < NEXP; ++e) acc[e] = 0.0;
#pragma unroll
  for (int it = 0; it < DMODEL / 4 / 64; ++it) {   // 8 iters
    int idx = it * 64 + lane;
    float4 xv = xr[idx];
#pragma unroll
    for (int e = 0; e < NEXP; ++e) {
      float4 gv = gr[e * (DMODEL / 4) + idx];
      acc[e] += (double)xv.x * gv.x + (double)xv.y * gv.y +
                (double)xv.z * gv.z + (double)xv.w * gv.w;
    }
  }
#pragma unroll
  for (int e = 0; e < NEXP; ++e) {
#pragma unroll
    for (int off = 32; off; off >>= 1) acc[e] += __shfl_down(acc[e], off, 64);
  }
  if (lane == 0) {
    int i0 = 0; double v0 = acc[0];
    for (int e = 1; e < NEXP; ++e) if (acc[e] > v0) { v0 = acc[e]; i0 = e; }
    int i1 = -1; double v1 = -1e300;
    for (int e = 0; e < NEXP; ++e) if (e != i0 && acc[e] > v1) { v1 = acc[e]; i1 = e; }
    double r = exp(v1 - v0);
    float w0 = (float)(1.0 / (1.0 + r));
    float w1 = 1.0f - w0;
    tkw[2 * t] = w0; tkw[2 * t + 1] = w1;
    tki[2 * t] = i0; tki[2 * t + 1] = i1;
    atomicAdd(&counts[i0], 1);
    atomicAdd(&counts[i1], 1);
  }
}

__global__ void k_scan(const int* __restrict__ counts, int* __restrict__ offs,
                       int* __restrict__ cursor) {
  if (threadIdx.x == 0) {
    int s = 0;
    for (int e = 0; e < NEXP; ++e) { offs[e] = s; cursor[e] = s; s += counts[e]; }
    offs[NEXP] = s;
  }
}

__global__ void k_assign(const int* __restrict__ tki, int* __restrict__ cursor,
                         int* __restrict__ pos, int* __restrict__ slot_tok) {
  int t = blockIdx.x * 256 + threadIdx.x;
  if (t >= T_TOK) return;
#pragma unroll
  for (int k = 0; k < 2; ++k) {
    int e = tki[2 * t + k];
    int p = atomicAdd(&cursor[e], 1);
    pos[2 * t + k] = p;
    slot_tok[p] = t;
  }
}

// ---------------- 256x256 NT bf16 GEMM, derived-wait 4-phase pipeline ----------------
// C[M,N] = A[M,K] * B[N,K]^T. 512 threads = 8 waves (2M x 4N). BK=64.
// LDS: 2 dbuf x (A 256x64 + B 256x64) bf16 = 128 KiB, XOR-swizzled (T2).
// Per K-tile t, 4 phases (1 barrier each), staging staggered for >=3-phase lead:
//   p1 (mq0,nq0): vmcnt(4); bar; read A02-half + B01; stage B01[t+1]; 16 MFMA
//   p2 (mq0,nq1): bar; read B23; stage B23[t+1]; 16 MFMA
//   p3 (mq1,nq0): vmcnt(6); bar; read A13-half (B01 regs kept); stage A13[t+1]; 16 MFMA
//   p4 (mq1,nq1): bar; re-read B23; stage A02[t+2] into CURRENT buf (A02 dead after p2); 16 MFMA
// Tail: t==NT-1 waits are (2, 0). Prologue stages tile0 (A02,B01,B23,A13) + A02[1].
template <int KD, bool PEREXP, bool GATHER, int EPI>
__launch_bounds__(512, 2)
__global__ void k_gemm8(const u16* __restrict__ A,
                        const u16* __restrict__ B1, const u16* __restrict__ B2,
                        size_t b_estride,
                        u16* __restrict__ C1, u16* __restrict__ C2,
                        float* __restrict__ OF, int nsplit,
                        const int* __restrict__ offs, const int* __restrict__ counts,
                        const int* __restrict__ slot_tok, int m_total) {
  constexpr int NT = KD / 64;
  static_assert(NT >= 2, "");
  __shared__ __attribute__((aligned(16))) u16 lds[2 * 32768];  // 128 KiB

  int e, base, cnt;
  if constexpr (PEREXP) { e = blockIdx.z; base = offs[e]; cnt = counts[e]; }
  else { e = 0; base = 0; cnt = m_total; }
  int m0 = blockIdx.y * 256;
  if (m0 >= cnt) return;
  int n0 = blockIdx.x * 256;

  int tid = threadIdx.x;
  int lane = tid & 63, wv = tid >> 6;
  int wm = wv >> 2, wn = wv & 3;
  int fr = lane & 15, fq = lane >> 4;

  // --- staging source pointers: 4 A-slabs + 4 B-slabs (64 rows each)
  int srow = tid >> 3;                     // wv*8 + (lane>>3), 0..63
  int sslot = (tid & 7) ^ (srow & 7);      // T2 pre-swizzle (involution)
  const u16* ap[4]; const u16* bp[4];
#pragma unroll
  for (int hs = 0; hs < 4; ++hs) {
    int r = hs * 64 + srow;                // tile row 0..255
    int ra = m0 + r; ra = ra < cnt ? ra : cnt - 1;
    int ga;
    if constexpr (GATHER) ga = slot_tok[base + ra];
    else                  ga = base + ra;
    ap[hs] = A + (size_t)ga * KD + sslot * 8;
    int nc = n0 + r;
    const u16* bb = (nc >= nsplit) ? (B2 + (size_t)(nc - nsplit) * KD)
                                   : (B1 + (size_t)nc * KD);
    bp[hs] = bb + b_estride * (size_t)e + sslot * 8;
  }

#define STG_A(hs, bufi, kt) gl16(ap[hs] + (size_t)(kt) * 64, \
                                 lds + (bufi) * 32768 + (hs) * 4096 + wv * 512)
#define STG_B(hs, bufi, kt) gl16(bp[hs] + (size_t)(kt) * 64, \
                                 lds + (bufi) * 32768 + 16384 + (hs) * 4096 + wv * 512)

  // --- read bases (u16 units); swizzled k-slot is lane-constant per ks
  int sKs0 = ((0 + fq) ^ (fr & 7)) * 8;
  int sKs1 = ((4 + fq) ^ (fr & 7)) * 8;
  int aBase = wm * 8192 + fr * 64;                                   // + i*1024
  int bBase = 16384 + (wn >> 1) * 8192 + ((wn & 1) * 64 + fr) * 64;  // + j*1024

  f32x4 acc[8][4];
#pragma unroll
  for (int i = 0; i < 8; ++i)
#pragma unroll
    for (int j = 0; j < 4; ++j) acc[i][j] = (f32x4){0.f, 0.f, 0.f, 0.f};

  // prologue: tile0 pairs [A02, B01, B23, A13], then A02 of tile1
  STG_A(0, 0, 0); STG_A(2, 0, 0);
  STG_B(0, 0, 0); STG_B(1, 0, 0);
  STG_B(2, 0, 0); STG_B(3, 0, 0);
  STG_A(1, 0, 0); STG_A(3, 0, 0);
  STG_A(0, 1, 1); STG_A(2, 1, 1);

  bf16x8 af[4][2], bkA[2][2], bkB[2][2];
  for (int t = 0; t < NT; ++t) {
    const int buf = t & 1, nbuf = buf ^ 1;
    const u16* lbuf = lds + buf * 32768;
    const bool hn1 = (t + 1) < NT, hn2 = (t + 2) < NT;

    // ---------- phase 1: (mq0, nq0) ----------
    if (t == NT - 1) asm volatile("s_waitcnt vmcnt(2)" ::: "memory");
    else             asm volatile("s_waitcnt vmcnt(4)" ::: "memory");
    BARRIER();
    __builtin_amdgcn_sched_barrier(0);
#pragma unroll
    for (int il = 0; il < 4; ++il) {
      af[il][0] = *(const bf16x8*)(lbuf + aBase + il * 1024 + sKs0);
      af[il][1] = *(const bf16x8*)(lbuf + aBase + il * 1024 + sKs1);
    }
#pragma unroll
    for (int jl = 0; jl < 2; ++jl) {
      bkA[jl][0] = *(const bf16x8*)(lbuf + bBase + jl * 1024 + sKs0);
      bkA[jl][1] = *(const bf16x8*)(lbuf + bBase + jl * 1024 + sKs1);
    }
    if (hn1) { STG_B(0, nbuf, t + 1); STG_B(1, nbuf, t + 1); }
    asm volatile("s_waitcnt lgkmcnt(0)" ::: "memory");
    __builtin_amdgcn_sched_barrier(0);
    __builtin_amdgcn_s_setprio(1);
#pragma unroll
    for (int il = 0; il < 4; ++il)
#pragma unroll
      for (int jl = 0; jl < 2; ++jl) {
        acc[il][jl] = __builtin_amdgcn_mfma_f32_16x16x32_bf16(af[il][0], bkA[jl][0], acc[il][jl], 0, 0, 0);
        acc[il][jl] = __builtin_amdgcn_mfma_f32_16x16x32_bf16(af[il][1], bkA[jl][1], acc[il][jl], 0, 0, 0);
      }
    __builtin_amdgcn_s_setprio(0);
    __builtin_amdgcn_sched_barrier(0);

    // ---------- phase 2: (mq0, nq1) ----------
    BARRIER();
    __builtin_amdgcn_sched_barrier(0);
#pragma unroll
    for (int jl = 0; jl < 2; ++jl) {
      bkB[jl][0] = *(const bf16x8*)(lbuf + bBase + (2 + jl) * 1024 + sKs0);
      bkB[jl][1] = *(const bf16x8*)(lbuf + bBase + (2 + jl) * 1024 + sKs1);
    }
    if (hn1) { STG_B(2, nbuf, t + 1); STG_B(3, nbuf, t + 1); }
    asm volatile("s_waitcnt lgkmcnt(0)" ::: "memory");
    __builtin_amdgcn_sched_barrier(0);
    __builtin_amdgcn_s_setprio(1);
#pragma unroll
    for (int il = 0; il < 4; ++il)
#pragma unroll
      for (int jl = 0; jl < 2; ++jl) {
        acc[il][2 + jl] = __builtin_amdgcn_mfma_f32_16x16x32_bf16(af[il][0], bkB[jl][0], acc[il][2 + jl], 0, 0, 0);
        acc[il][2 + jl] = __builtin_amdgcn_mfma_f32_16x16x32_bf16(af[il][1], bkB[jl][1], acc[il][2 + jl], 0, 0, 0);
      }
    __builtin_amdgcn_s_setprio(0);
    __builtin_amdgcn_sched_barrier(0);

    // ---------- phase 3: (mq1, nq0) ----------
    if (t == NT - 1) asm volatile("s_waitcnt vmcnt(0)" ::: "memory");
    else             asm volatile("s_waitcnt vmcnt(6)" ::: "memory");
    BARRIER();
    __builtin_amdgcn_sched_barrier(0);
#pragma unroll
    for (int il = 0; il < 4; ++il) {
      af[il][0] = *(const bf16x8*)(lbuf + aBase + (4 + il) * 1024 + sKs0);
      af[il][1] = *(const bf16x8*)(lbuf + aBase + (4 + il) * 1024 + sKs1);
    }
    if (hn1) { STG_A(1, nbuf, t + 1); STG_A(3, nbuf, t + 1); }
    asm volatile("s_waitcnt lgkmcnt(0)" ::: "memory");
    __builtin_amdgcn_sched_barrier(0);
    __builtin_amdgcn_s_setprio(1);
#pragma unroll
    for (int il = 0; il < 4; ++il)
#pragma unroll
      for (int jl = 0; jl < 2; ++jl) {
        acc[4 + il][jl] = __builtin_amdgcn_mfma_f32_16x16x32_bf16(af[il][0], bkA[jl][0], acc[4 + il][jl], 0, 0, 0);
        acc[4 + il][jl] = __builtin_amdgcn_mfma_f32_16x16x32_bf16(af[il][1], bkA[jl][1], acc[4 + il][jl], 0, 0, 0);
      }
    __builtin_amdgcn_s_setprio(0);
    __builtin_amdgcn_sched_barrier(0);

    // ---------- phase 4: (mq1, nq1) ----------
    BARRIER();
    __builtin_amdgcn_sched_barrier(0);
#pragma unroll
    for (int jl = 0; jl < 2; ++jl) {
      bkB[jl][0] = *(const bf16x8*)(lbuf + bBase + (2 + jl) * 1024 + sKs0);
      bkB[jl][1] = *(const bf16x8*)(lbuf + bBase + (2 + jl) * 1024 + sKs1);
    }
    if (hn2) { STG_A(0, buf, t + 2); STG_A(2, buf, t + 2); }  // A02 of buf dead since p2
    asm volatile("s_waitcnt lgkmcnt(0)" ::: "memory");
    __builtin_amdgcn_sched_barrier(0);
    __builtin_amdgcn_s_setprio(1);
#pragma unroll
    for (int il = 0; il < 4; ++il)
#pragma unroll
      for (int jl = 0; jl < 2; ++jl) {
        acc[4 + il][2 + jl] = __builtin_amdgcn_mfma_f32_16x16x32_bf16(af[il][0], bkB[jl][0], acc[4 + il][2 + jl], 0, 0, 0);
        acc[4 + il][2 + jl] = __builtin_amdgcn_mfma_f32_16x16x32_bf16(af[il][1], bkB[jl][1], acc[4 + il][2 + jl], 0, 0, 0);
      }
    __builtin_amdgcn_s_setprio(0);
    __builtin_amdgcn_sched_barrier(0);
  }
#undef STG_A
#undef STG_B

  // --- epilogue ---
#pragma unroll
  for (int i = 0; i < 8; ++i) {
    int row_t = wm * 128 + i * 16 + fq * 4;
#pragma unroll
    for (int r = 0; r < 4; ++r) {
      int m = m0 + row_t + r;
      if (m >= cnt) continue;
      size_t rowoff = (size_t)(base + m) * (size_t)nsplit;
#pragma unroll
      for (int j = 0; j < 4; ++j) {
        int col_t = n0 + wn * 64 + j * 16 + fr;
        float v = acc[i][j][r];
        if constexpr (EPI == 2) {
          OF[rowoff + col_t] = v;
        } else {
          if (col_t >= nsplit) C2[rowoff + col_t - nsplit] = f2bf(v);
          else                 C1[rowoff + col_t] = f2bf(v);
        }
      }
    }
  }
}

// ---------------- h = silu(g) * u ----------------
__global__ void k_silu_mul(const u16* __restrict__ g, const u16* __restrict__ u,
                           u16* __restrict__ h, int n8) {
  int i = blockIdx.x * 256 + threadIdx.x;
  if (i >= n8) return;
  s16x8 gv = ((const s16x8*)g)[i];
  s16x8 uv = ((const s16x8*)u)[i];
  s16x8 hv;
#pragma unroll
  for (int j = 0; j < 8; ++j) {
    float gf = bf2f((u16)gv[j]);
    float uf = bf2f((u16)uv[j]);
    float s = gf / (1.f + __expf(-gf));
    hv[j] = (short)f2bf(s * uf);
  }
  ((s16x8*)h)[i] = hv;
}

// ---------------- y[t] += w0*yr[pos0] + w1*yr[pos1] ----------------
__global__ void k_combine(float* __restrict__ y, const u16* __restrict__ yr,
                          const float* __restrict__ tkw, const int* __restrict__ pos) {
  int t = blockIdx.x;
  int i = threadIdx.x;
  float w0 = tkw[2 * t], w1 = tkw[2 * t + 1];
  size_t p0 = (size_t)pos[2 * t] * DMODEL, p1 = (size_t)pos[2 * t + 1] * DMODEL;
  int d0 = i * 8;
  s16x8 a = *(const s16x8*)(yr + p0 + d0);
  s16x8 b = *(const s16x8*)(yr + p1 + d0);
  float* yo = y + (size_t)t * DMODEL + d0;
#pragma unroll
  for (int j = 0; j < 8; ++j)
    yo[j] += w0 * bf2f((u16)a[j]) + w1 * bf2f((u16)b[j]);
}

extern "C" void kernel_launch(void* const* d_in, const int* in_sizes, int n_in,
                              void* d_out, int out_size, void* d_ws, size_t ws_size,
                              hipStream_t stream) {
  const float* x   = (const float*)d_in[0];
  const float* gw  = (const float*)d_in[1];
  const float* wg  = (const float*)d_in[2];
  const float* wu  = (const float*)d_in[3];
  const float* wd  = (const float*)d_in[4];
  const float* wsg = (const float*)d_in[5];
  const float* wsu = (const float*)d_in[6];
  const float* wsd = (const float*)d_in[7];
  float* out = (float*)d_out;

  char* ws = (char*)d_ws;
  size_t o = 0;
  auto alloc = [&](size_t bytes) -> void* {
    void* p = ws + o;
    o += (bytes + 255) & ~(size_t)255;
    return p;
  };
  u16* xb   = (u16*)alloc((size_t)T_TOK * DMODEL * 2);
  u16* wbg  = (u16*)alloc((size_t)NEXP * DFF * DMODEL * 2);
  u16* wbu  = (u16*)alloc((size_t)NEXP * DFF * DMODEL * 2);
  u16* wbd  = (u16*)alloc((size_t)NEXP * DMODEL * DFF * 2);
  u16* wbsg = (u16*)alloc((size_t)DFFS * DMODEL * 2);
  u16* wbsu = (u16*)alloc((size_t)DFFS * DMODEL * 2);
  u16* wbsd = (u16*)alloc((size_t)DMODEL * DFFS * 2);
  u16* P1   = (u16*)alloc((size_t)NSLOT * DFF * 2);   // == T_TOK*DFFS*2
  u16* P2   = (u16*)alloc((size_t)NSLOT * DFF * 2);
  u16* yr   = (u16*)alloc((size_t)NSLOT * DMODEL * 2);
  float* tkw = (float*)alloc((size_t)T_TOK * 2 * 4);
  int* tki   = (int*)alloc((size_t)T_TOK * 2 * 4);
  int* pos   = (int*)alloc((size_t)T_TOK * 2 * 4);
  int* slot_tok = (int*)alloc((size_t)NSLOT * 4);
  int* counts   = (int*)alloc(64);
  int* offs     = (int*)alloc(64);
  int* cursor   = (int*)alloc(64);
  if (o > ws_size) {
    fprintf(stderr, "kernel_launch: ws too small: need %zu have %zu\n", o, ws_size);
    return;
  }

  // --- conversions fp32 -> bf16 ---
  {
    int n8x = T_TOK * DMODEL / 8;
    k_convert<<<(n8x + 255) / 256, 256, 0, stream>>>(x, xb, n8x);
    int n8w = NEXP * DFF * DMODEL / 8;
    k_convert<<<(n8w + 255) / 256, 256, 0, stream>>>(wg, wbg, n8w);
    k_convert<<<(n8w + 255) / 256, 256, 0, stream>>>(wu, wbu, n8w);
    k_convert<<<(n8w + 255) / 256, 256, 0, stream>>>(wd, wbd, n8w);
    int n8s = DFFS * DMODEL / 8;
    k_convert<<<(n8s + 255) / 256, 256, 0, stream>>>(wsg, wbsg, n8s);
    k_convert<<<(n8s + 255) / 256, 256, 0, stream>>>(wsu, wbsu, n8s);
    k_convert<<<(n8s + 255) / 256, 256, 0, stream>>>(wsd, wbsd, n8s);
  }

  // --- routing ---
  k_zero<<<1, 64, 0, stream>>>(counts);
  k_router<<<T_TOK, 64, 0, stream>>>(x, gw, tkw, tki, counts);
  k_scan<<<1, 64, 0, stream>>>(counts, offs, cursor);
  k_assign<<<(T_TOK + 255) / 256, 256, 0, stream>>>(tki, cursor, pos, slot_tok);

  size_t estride_gu = (size_t)DFF * DMODEL;
  size_t estride_d  = (size_t)DMODEL * DFF;

  // --- routed experts: fused gate+up (N span = 2816 = 11 n-blocks) ---
  k_gemm8<DMODEL, true, true, 0><<<dim3(11, 16, 8), 512, 0, stream>>>(
      xb, wbg, wbu, estride_gu, P1, P2, nullptr, DFF, offs, counts, slot_tok, 0);
  {
    int n8 = NSLOT * DFF / 8;
    k_silu_mul<<<(n8 + 255) / 256, 256, 0, stream>>>(P1, P2, P1, n8);  // in-place
  }
  k_gemm8<DFF, true, false, 0><<<dim3(8, 16, 8), 512, 0, stream>>>(
      P1, wbd, wbd, estride_d, yr, yr, nullptr, DMODEL, offs, counts, nullptr, 0);

  // --- shared experts: fused gate+up (N span = 5632 = 22 n-blocks) ---
  k_gemm8<DMODEL, false, false, 0><<<dim3(22, 16, 1), 512, 0, stream>>>(
      xb, wbsg, wbsu, 0, P1, P2, nullptr, DFFS, nullptr, nullptr, nullptr, T_TOK);
  {
    int n8 = T_TOK * DFFS / 8;
    k_silu_mul<<<(n8 + 255) / 256, 256, 0, stream>>>(P1, P2, P1, n8);  // in-place
  }
  k_gemm8<DFFS, false, false, 2><<<dim3(8, 16, 1), 512, 0, stream>>>(
      P1, wbsd, wbsd, 0, yr, yr, out, DMODEL, nullptr, nullptr, nullptr, T_TOK);

  // --- combine routed into output ---
  k_combine<<<T_TOK, 256, 0, stream>>>(out, yr, tkw, pos);
}

// Round 5
// 644.373 us; speedup vs baseline: 1.2152x; 1.0570x over previous
//
#include <hip/hip_runtime.h>
#include <stdint.h>
#include <stdio.h>

#define T_TOK 4096
#define DMODEL 2048
#define NEXP 8
#define DFF 1408
#define DFFS 2816
#define NSLOT 8192   // T_TOK * 2

typedef unsigned short u16;
typedef short s16x8 __attribute__((ext_vector_type(8)));
typedef unsigned short u16x4 __attribute__((ext_vector_type(4)));
typedef __bf16 bf16x8 __attribute__((ext_vector_type(8)));
typedef float f32x4 __attribute__((ext_vector_type(4)));

__device__ __forceinline__ u16 f2bf(float f) {
  uint32_t u = __builtin_bit_cast(uint32_t, f);
  u += 0x7fffu + ((u >> 16) & 1u);
  return (u16)(u >> 16);
}
__device__ __forceinline__ float bf2f(u16 h) {
  uint32_t u = ((uint32_t)h) << 16;
  return __builtin_bit_cast(float, u);
}

// async global->LDS, 16B per lane; LDS dest = wave-uniform base + lane*16
__device__ __forceinline__ void gl16(const u16* g, u16* l) {
  __builtin_amdgcn_global_load_lds((const __attribute__((address_space(1))) void*)g,
                                   (__attribute__((address_space(3))) void*)l,
                                   16, 0, 0);
}

#define BARRIER() asm volatile("s_barrier" ::: "memory")

// ---------------- fp32 -> bf16 convert (8 elems/thread) ----------------
__global__ void k_convert(const float* __restrict__ in, u16* __restrict__ out, int n8) {
  int i = blockIdx.x * 256 + threadIdx.x;
  if (i >= n8) return;
  float4 a = ((const float4*)in)[2 * i];
  float4 b = ((const float4*)in)[2 * i + 1];
  s16x8 r;
  r[0] = (short)f2bf(a.x); r[1] = (short)f2bf(a.y);
  r[2] = (short)f2bf(a.z); r[3] = (short)f2bf(a.w);
  r[4] = (short)f2bf(b.x); r[5] = (short)f2bf(b.y);
  r[6] = (short)f2bf(b.z); r[7] = (short)f2bf(b.w);
  ((s16x8*)out)[i] = r;
}

__global__ void k_zero(int* __restrict__ counts) {
  if (threadIdx.x < NEXP) counts[threadIdx.x] = 0;
}

// ---------------- router: 4 waves/token, 2 experts/wave, fused x->bf16 ----------------
// Per-expert summation order is BITWISE IDENTICAL to the previous (passing)
// router: partials at idx = it*64+lane, 4 chained adds per float4, shuffle-down
// reduce 32..1. Only the expert->wave mapping changed (no change in values).
__global__ void k_router(const float* __restrict__ x, const float* __restrict__ gw,
                         u16* __restrict__ xb,
                         float* __restrict__ tkw, int* __restrict__ tki,
                         int* __restrict__ counts) {
  __shared__ double sm[NEXP];
  int t = blockIdx.x;
  int tid = threadIdx.x;
  int lane = tid & 63, wv = tid >> 6;     // 4 waves
  const float4* xr = (const float4*)(x + (size_t)t * DMODEL);
  const float4* gr = (const float4*)gw;
  int e0 = wv * 2, e1 = e0 + 1;
  double a0 = 0.0, a1 = 0.0;
#pragma unroll
  for (int it = 0; it < DMODEL / 4 / 64; ++it) {   // 8 iters
    int idx = it * 64 + lane;
    float4 xv = xr[idx];
    float4 g0 = gr[e0 * (DMODEL / 4) + idx];
    float4 g1 = gr[e1 * (DMODEL / 4) + idx];
    a0 += (double)xv.x * g0.x + (double)xv.y * g0.y +
          (double)xv.z * g0.z + (double)xv.w * g0.w;
    a1 += (double)xv.x * g1.x + (double)xv.y * g1.y +
          (double)xv.z * g1.z + (double)xv.w * g1.w;
    if (wv == 0) {   // fused x -> bf16 (wave 0 only)
      u16x4 r = { f2bf(xv.x), f2bf(xv.y), f2bf(xv.z), f2bf(xv.w) };
      ((u16x4*)(xb + (size_t)t * DMODEL))[idx] = r;
    }
  }
#pragma unroll
  for (int off = 32; off; off >>= 1) {
    a0 += __shfl_down(a0, off, 64);
    a1 += __shfl_down(a1, off, 64);
  }
  if (lane == 0) { sm[e0] = a0; sm[e1] = a1; }
  __syncthreads();
  if (tid == 0) {
    double acc[NEXP];
#pragma unroll
    for (int e = 0; e < NEXP; ++e) acc[e] = sm[e];
    int i0 = 0; double v0 = acc[0];
    for (int e = 1; e < NEXP; ++e) if (acc[e] > v0) { v0 = acc[e]; i0 = e; }
    int i1 = -1; double v1 = -1e300;
    for (int e = 0; e < NEXP; ++e) if (e != i0 && acc[e] > v1) { v1 = acc[e]; i1 = e; }
    double r = exp(v1 - v0);
    float w0 = (float)(1.0 / (1.0 + r));
    float w1 = 1.0f - w0;
    tkw[2 * t] = w0; tkw[2 * t + 1] = w1;
    tki[2 * t] = i0; tki[2 * t + 1] = i1;
    atomicAdd(&counts[i0], 1);
    atomicAdd(&counts[i1], 1);
  }
}

__global__ void k_scan(const int* __restrict__ counts, int* __restrict__ offs,
                       int* __restrict__ cursor) {
  if (threadIdx.x == 0) {
    int s = 0;
    for (int e = 0; e < NEXP; ++e) { offs[e] = s; cursor[e] = s; s += counts[e]; }
    offs[NEXP] = s;
  }
}

__global__ void k_assign(const int* __restrict__ tki, int* __restrict__ cursor,
                         int* __restrict__ pos, int* __restrict__ slot_tok) {
  int t = blockIdx.x * 256 + threadIdx.x;
  if (t >= T_TOK) return;
#pragma unroll
  for (int k = 0; k < 2; ++k) {
    int e = tki[2 * t + k];
    int p = atomicAdd(&cursor[e], 1);
    pos[2 * t + k] = p;
    slot_tok[p] = t;
  }
}

// ---------------- 256x256 NT bf16 GEMM, derived-wait 4-phase pipeline ----------------
// C[M,N] = A[M,K] * B[N,K]^T. 512 threads = 8 waves (2M x 4N). BK=64.
// LDS: 2 dbuf x (A 256x64 + B 256x64) bf16 = 128 KiB, XOR-swizzled (T2).
// Per K-tile t, 4 phases (1 barrier each), staging staggered for >=3-phase lead:
//   p1 (mq0,nq0): vmcnt(4); bar; read A02-half + B01; stage B01[t+1]; 16 MFMA
//   p2 (mq0,nq1): bar; read B23; stage B23[t+1]; 16 MFMA
//   p3 (mq1,nq0): vmcnt(6); bar; read A13-half (B01 regs kept); stage A13[t+1]; 16 MFMA
//   p4 (mq1,nq1): bar; re-read B23; stage A02[t+2] into CURRENT buf (A02 dead after p2); 16 MFMA
// Tail: t==NT-1 waits are (2, 0). Prologue stages tile0 (A02,B01,B23,A13) + A02[1].
template <int KD, bool PEREXP, bool GATHER, int EPI>
__launch_bounds__(512, 2)
__global__ void k_gemm8(const u16* __restrict__ A,
                        const u16* __restrict__ B1, const u16* __restrict__ B2,
                        size_t b_estride,
                        u16* __restrict__ C1, u16* __restrict__ C2,
                        float* __restrict__ OF, int nsplit,
                        const int* __restrict__ offs, const int* __restrict__ counts,
                        const int* __restrict__ slot_tok, int m_total) {
  constexpr int NT = KD / 64;
  static_assert(NT >= 2, "");
  __shared__ __attribute__((aligned(16))) u16 lds[2 * 32768];  // 128 KiB

  int e, base, cnt;
  if constexpr (PEREXP) { e = blockIdx.z; base = offs[e]; cnt = counts[e]; }
  else { e = 0; base = 0; cnt = m_total; }
  int m0 = blockIdx.y * 256;
  if (m0 >= cnt) return;
  int n0 = blockIdx.x * 256;

  int tid = threadIdx.x;
  int lane = tid & 63, wv = tid >> 6;
  int wm = wv >> 2, wn = wv & 3;
  int fr = lane & 15, fq = lane >> 4;

  // --- staging source pointers: 4 A-slabs + 4 B-slabs (64 rows each)
  int srow = tid >> 3;                     // wv*8 + (lane>>3), 0..63
  int sslot = (tid & 7) ^ (srow & 7);      // T2 pre-swizzle (involution)
  const u16* ap[4]; const u16* bp[4];
#pragma unroll
  for (int hs = 0; hs < 4; ++hs) {
    int r = hs * 64 + srow;                // tile row 0..255
    int ra = m0 + r; ra = ra < cnt ? ra : cnt - 1;
    int ga;
    if constexpr (GATHER) ga = slot_tok[base + ra];
    else                  ga = base + ra;
    ap[hs] = A + (size_t)ga * KD + sslot * 8;
    int nc = n0 + r;
    const u16* bb = (nc >= nsplit) ? (B2 + (size_t)(nc - nsplit) * KD)
                                   : (B1 + (size_t)nc * KD);
    bp[hs] = bb + b_estride * (size_t)e + sslot * 8;
  }

#define STG_A(hs, bufi, kt) gl16(ap[hs] + (size_t)(kt) * 64, \
                                 lds + (bufi) * 32768 + (hs) * 4096 + wv * 512)
#define STG_B(hs, bufi, kt) gl16(bp[hs] + (size_t)(kt) * 64, \
                                 lds + (bufi) * 32768 + 16384 + (hs) * 4096 + wv * 512)

  // --- read bases (u16 units); swizzled k-slot is lane-constant per ks
  int sKs0 = ((0 + fq) ^ (fr & 7)) * 8;
  int sKs1 = ((4 + fq) ^ (fr & 7)) * 8;
  int aBase = wm * 8192 + fr * 64;                                   // + i*1024
  int bBase = 16384 + (wn >> 1) * 8192 + ((wn & 1) * 64 + fr) * 64;  // + j*1024

  f32x4 acc[8][4];
#pragma unroll
  for (int i = 0; i < 8; ++i)
#pragma unroll
    for (int j = 0; j < 4; ++j) acc[i][j] = (f32x4){0.f, 0.f, 0.f, 0.f};

  // prologue: tile0 pairs [A02, B01, B23, A13], then A02 of tile1
  STG_A(0, 0, 0); STG_A(2, 0, 0);
  STG_B(0, 0, 0); STG_B(1, 0, 0);
  STG_B(2, 0, 0); STG_B(3, 0, 0);
  STG_A(1, 0, 0); STG_A(3, 0, 0);
  STG_A(0, 1, 1); STG_A(2, 1, 1);

  bf16x8 af[4][2], bkA[2][2], bkB[2][2];
  for (int t = 0; t < NT; ++t) {
    const int buf = t & 1, nbuf = buf ^ 1;
    const u16* lbuf = lds + buf * 32768;
    const bool hn1 = (t + 1) < NT, hn2 = (t + 2) < NT;

    // ---------- phase 1: (mq0, nq0) ----------
    if (t == NT - 1) asm volatile("s_waitcnt vmcnt(2)" ::: "memory");
    else             asm volatile("s_waitcnt vmcnt(4)" ::: "memory");
    BARRIER();
    __builtin_amdgcn_sched_barrier(0);
#pragma unroll
    for (int il = 0; il < 4; ++il) {
      af[il][0] = *(const bf16x8*)(lbuf + aBase + il * 1024 + sKs0);
      af[il][1] = *(const bf16x8*)(lbuf + aBase + il * 1024 + sKs1);
    }
#pragma unroll
    for (int jl = 0; jl < 2; ++jl) {
      bkA[jl][0] = *(const bf16x8*)(lbuf + bBase + jl * 1024 + sKs0);
      bkA[jl][1] = *(const bf16x8*)(lbuf + bBase + jl * 1024 + sKs1);
    }
    if (hn1) { STG_B(0, nbuf, t + 1); STG_B(1, nbuf, t + 1); }
    asm volatile("s_waitcnt lgkmcnt(0)" ::: "memory");
    __builtin_amdgcn_sched_barrier(0);
    __builtin_amdgcn_s_setprio(1);
#pragma unroll
    for (int il = 0; il < 4; ++il)
#pragma unroll
      for (int jl = 0; jl < 2; ++jl) {
        acc[il][jl] = __builtin_amdgcn_mfma_f32_16x16x32_bf16(af[il][0], bkA[jl][0], acc[il][jl], 0, 0, 0);
        acc[il][jl] = __builtin_amdgcn_mfma_f32_16x16x32_bf16(af[il][1], bkA[jl][1], acc[il][jl], 0, 0, 0);
      }
    __builtin_amdgcn_s_setprio(0);
    __builtin_amdgcn_sched_barrier(0);

    // ---------- phase 2: (mq0, nq1) ----------
    BARRIER();
    __builtin_amdgcn_sched_barrier(0);
#pragma unroll
    for (int jl = 0; jl < 2; ++jl) {
      bkB[jl][0] = *(const bf16x8*)(lbuf + bBase + (2 + jl) * 1024 + sKs0);
      bkB[jl][1] = *(const bf16x8*)(lbuf + bBase + (2 + jl) * 1024 + sKs1);
    }
    if (hn1) { STG_B(2, nbuf, t + 1); STG_B(3, nbuf, t + 1); }
    asm volatile("s_waitcnt lgkmcnt(0)" ::: "memory");
    __builtin_amdgcn_sched_barrier(0);
    __builtin_amdgcn_s_setprio(1);
#pragma unroll
    for (int il = 0; il < 4; ++il)
#pragma unroll
      for (int jl = 0; jl < 2; ++jl) {
        acc[il][2 + jl] = __builtin_amdgcn_mfma_f32_16x16x32_bf16(af[il][0], bkB[jl][0], acc[il][2 + jl], 0, 0, 0);
        acc[il][2 + jl] = __builtin_amdgcn_mfma_f32_16x16x32_bf16(af[il][1], bkB[jl][1], acc[il][2 + jl], 0, 0, 0);
      }
    __builtin_amdgcn_s_setprio(0);
    __builtin_amdgcn_sched_barrier(0);

    // ---------- phase 3: (mq1, nq0) ----------
    if (t == NT - 1) asm volatile("s_waitcnt vmcnt(0)" ::: "memory");
    else             asm volatile("s_waitcnt vmcnt(6)" ::: "memory");
    BARRIER();
    __builtin_amdgcn_sched_barrier(0);
#pragma unroll
    for (int il = 0; il < 4; ++il) {
      af[il][0] = *(const bf16x8*)(lbuf + aBase + (4 + il) * 1024 + sKs0);
      af[il][1] = *(const bf16x8*)(lbuf + aBase + (4 + il) * 1024 + sKs1);
    }
    if (hn1) { STG_A(1, nbuf, t + 1); STG_A(3, nbuf, t + 1); }
    asm volatile("s_waitcnt lgkmcnt(0)" ::: "memory");
    __builtin_amdgcn_sched_barrier(0);
    __builtin_amdgcn_s_setprio(1);
#pragma unroll
    for (int il = 0; il < 4; ++il)
#pragma unroll
      for (int jl = 0; jl < 2; ++jl) {
        acc[4 + il][jl] = __builtin_amdgcn_mfma_f32_16x16x32_bf16(af[il][0], bkA[jl][0], acc[4 + il][jl], 0, 0, 0);
        acc[4 + il][jl] = __builtin_amdgcn_mfma_f32_16x16x32_bf16(af[il][1], bkA[jl][1], acc[4 + il][jl], 0, 0, 0);
      }
    __builtin_amdgcn_s_setprio(0);
    __builtin_amdgcn_sched_barrier(0);

    // ---------- phase 4: (mq1, nq1) ----------
    BARRIER();
    __builtin_amdgcn_sched_barrier(0);
#pragma unroll
    for (int jl = 0; jl < 2; ++jl) {
      bkB[jl][0] = *(const bf16x8*)(lbuf + bBase + (2 + jl) * 1024 + sKs0);
      bkB[jl][1] = *(const bf16x8*)(lbuf + bBase + (2 + jl) * 1024 + sKs1);
    }
    if (hn2) { STG_A(0, buf, t + 2); STG_A(2, buf, t + 2); }  // A02 of buf dead since p2
    asm volatile("s_waitcnt lgkmcnt(0)" ::: "memory");
    __builtin_amdgcn_sched_barrier(0);
    __builtin_amdgcn_s_setprio(1);
#pragma unroll
    for (int il = 0; il < 4; ++il)
#pragma unroll
      for (int jl = 0; jl < 2; ++jl) {
        acc[4 + il][2 + jl] = __builtin_amdgcn_mfma_f32_16x16x32_bf16(af[il][0], bkB[jl][0], acc[4 + il][2 + jl], 0, 0, 0);
        acc[4 + il][2 + jl] = __builtin_amdgcn_mfma_f32_16x16x32_bf16(af[il][1], bkB[jl][1], acc[4 + il][2 + jl], 0, 0, 0);
      }
    __builtin_amdgcn_s_setprio(0);
    __builtin_amdgcn_sched_barrier(0);
  }
#undef STG_A
#undef STG_B

  // --- epilogue ---
#pragma unroll
  for (int i = 0; i < 8; ++i) {
    int row_t = wm * 128 + i * 16 + fq * 4;
#pragma unroll
    for (int r = 0; r < 4; ++r) {
      int m = m0 + row_t + r;
      if (m >= cnt) continue;
      size_t rowoff = (size_t)(base + m) * (size_t)nsplit;
#pragma unroll
      for (int j = 0; j < 4; ++j) {
        int col_t = n0 + wn * 64 + j * 16 + fr;
        float v = acc[i][j][r];
        if constexpr (EPI == 2) {
          OF[rowoff + col_t] = v;
        } else {
          if (col_t >= nsplit) C2[rowoff + col_t - nsplit] = f2bf(v);
          else                 C1[rowoff + col_t] = f2bf(v);
        }
      }
    }
  }
}

// ---------------- h = silu(g) * u ----------------
__global__ void k_silu_mul(const u16* __restrict__ g, const u16* __restrict__ u,
                           u16* __restrict__ h, int n8) {
  int i = blockIdx.x * 256 + threadIdx.x;
  if (i >= n8) return;
  s16x8 gv = ((const s16x8*)g)[i];
  s16x8 uv = ((const s16x8*)u)[i];
  s16x8 hv;
#pragma unroll
  for (int j = 0; j < 8; ++j) {
    float gf = bf2f((u16)gv[j]);
    float uf = bf2f((u16)uv[j]);
    float s = gf / (1.f + __expf(-gf));
    hv[j] = (short)f2bf(s * uf);
  }
  ((s16x8*)h)[i] = hv;
}

// ---------------- y[t] += w0*yr[pos0] + w1*yr[pos1] ----------------
__global__ void k_combine(float* __restrict__ y, const u16* __restrict__ yr,
                          const float* __restrict__ tkw, const int* __restrict__ pos) {
  int t = blockIdx.x;
  int i = threadIdx.x;
  float w0 = tkw[2 * t], w1 = tkw[2 * t + 1];
  size_t p0 = (size_t)pos[2 * t] * DMODEL, p1 = (size_t)pos[2 * t + 1] * DMODEL;
  int d0 = i * 8;
  s16x8 a = *(const s16x8*)(yr + p0 + d0);
  s16x8 b = *(const s16x8*)(yr + p1 + d0);
  float* yo = y + (size_t)t * DMODEL + d0;
#pragma unroll
  for (int j = 0; j < 8; ++j)
    yo[j] += w0 * bf2f((u16)a[j]) + w1 * bf2f((u16)b[j]);
}

extern "C" void kernel_launch(void* const* d_in, const int* in_sizes, int n_in,
                              void* d_out, int out_size, void* d_ws, size_t ws_size,
                              hipStream_t stream) {
  const float* x   = (const float*)d_in[0];
  const float* gw  = (const float*)d_in[1];
  const float* wg  = (const float*)d_in[2];
  const float* wu  = (const float*)d_in[3];
  const float* wd  = (const float*)d_in[4];
  const float* wsg = (const float*)d_in[5];
  const float* wsu = (const float*)d_in[6];
  const float* wsd = (const float*)d_in[7];
  float* out = (float*)d_out;

  char* ws = (char*)d_ws;
  size_t o = 0;
  auto alloc = [&](size_t bytes) -> void* {
    void* p = ws + o;
    o += (bytes + 255) & ~(size_t)255;
    return p;
  };
  u16* xb   = (u16*)alloc((size_t)T_TOK * DMODEL * 2);
  u16* wbg  = (u16*)alloc((size_t)NEXP * DFF * DMODEL * 2);
  u16* wbu  = (u16*)alloc((size_t)NEXP * DFF * DMODEL * 2);
  u16* wbd  = (u16*)alloc((size_t)NEXP * DMODEL * DFF * 2);
  u16* wbsg = (u16*)alloc((size_t)DFFS * DMODEL * 2);
  u16* wbsu = (u16*)alloc((size_t)DFFS * DMODEL * 2);
  u16* wbsd = (u16*)alloc((size_t)DMODEL * DFFS * 2);
  u16* P1   = (u16*)alloc((size_t)NSLOT * DFF * 2);   // == T_TOK*DFFS*2
  u16* P2   = (u16*)alloc((size_t)NSLOT * DFF * 2);
  u16* yr   = (u16*)alloc((size_t)NSLOT * DMODEL * 2);
  float* tkw = (float*)alloc((size_t)T_TOK * 2 * 4);
  int* tki   = (int*)alloc((size_t)T_TOK * 2 * 4);
  int* pos   = (int*)alloc((size_t)T_TOK * 2 * 4);
  int* slot_tok = (int*)alloc((size_t)NSLOT * 4);
  int* counts   = (int*)alloc(64);
  int* offs     = (int*)alloc(64);
  int* cursor   = (int*)alloc(64);
  if (o > ws_size) {
    fprintf(stderr, "kernel_launch: ws too small: need %zu have %zu\n", o, ws_size);
    return;
  }

  // --- conversions fp32 -> bf16 (x conversion is fused into k_router) ---
  {
    int n8w = NEXP * DFF * DMODEL / 8;
    k_convert<<<(n8w + 255) / 256, 256, 0, stream>>>(wg, wbg, n8w);
    k_convert<<<(n8w + 255) / 256, 256, 0, stream>>>(wu, wbu, n8w);
    k_convert<<<(n8w + 255) / 256, 256, 0, stream>>>(wd, wbd, n8w);
    int n8s = DFFS * DMODEL / 8;
    k_convert<<<(n8s + 255) / 256, 256, 0, stream>>>(wsg, wbsg, n8s);
    k_convert<<<(n8s + 255) / 256, 256, 0, stream>>>(wsu, wbsu, n8s);
    k_convert<<<(n8s + 255) / 256, 256, 0, stream>>>(wsd, wbsd, n8s);
  }

  // --- routing (also produces xb) ---
  k_zero<<<1, 64, 0, stream>>>(counts);
  k_router<<<T_TOK, 256, 0, stream>>>(x, gw, xb, tkw, tki, counts);
  k_scan<<<1, 64, 0, stream>>>(counts, offs, cursor);
  k_assign<<<(T_TOK + 255) / 256, 256, 0, stream>>>(tki, cursor, pos, slot_tok);

  size_t estride_gu = (size_t)DFF * DMODEL;
  size_t estride_d  = (size_t)DMODEL * DFF;

  // --- routed experts: fused gate+up (N span = 2816 = 11 n-blocks) ---
  k_gemm8<DMODEL, true, true, 0><<<dim3(11, 16, 8), 512, 0, stream>>>(
      xb, wbg, wbu, estride_gu, P1, P2, nullptr, DFF, offs, counts, slot_tok, 0);
  {
    int n8 = NSLOT * DFF / 8;
    k_silu_mul<<<(n8 + 255) / 256, 256, 0, stream>>>(P1, P2, P1, n8);  // in-place
  }
  k_gemm8<DFF, true, false, 0><<<dim3(8, 16, 8), 512, 0, stream>>>(
      P1, wbd, wbd, estride_d, yr, yr, nullptr, DMODEL, offs, counts, nullptr, 0);

  // --- shared experts: fused gate+up (N span = 5632 = 22 n-blocks) ---
  k_gemm8<DMODEL, false, false, 0><<<dim3(22, 16, 1), 512, 0, stream>>>(
      xb, wbsg, wbsu, 0, P1, P2, nullptr, DFFS, nullptr, nullptr, nullptr, T_TOK);
  {
    int n8 = T_TOK * DFFS / 8;
    k_silu_mul<<<(n8 + 255) / 256, 256, 0, stream>>>(P1, P2, P1, n8);  // in-place
  }
  k_gemm8<DFFS, false, false, 2><<<dim3(8, 16, 1), 512, 0, stream>>>(
      P1, wbsd, wbsd, 0, yr, yr, out, DMODEL, nullptr, nullptr, nullptr, T_TOK);

  // --- combine routed into output ---
  k_combine<<<T_TOK, 256, 0, stream>>>(out, yr, tkw, pos);
}

// Round 6
// 590.390 us; speedup vs baseline: 1.3264x; 1.0914x over previous
//
#include <hip/hip_runtime.h>
#include <stdint.h>
#include <stdio.h>

#define T_TOK 4096
#define DMODEL 2048
#define NEXP 8
#define DFF 1408
#define DFFS 2816
#define NSLOT 8192   // T_TOK * 2

// schedule-table grid bounds (worst case): routed m-blocks sum <= 39
#define GU_GRID (16 * 22 + 39 * 11)   // 781
#define DN_GRID (16 * 8 + 39 * 8)     // 440

typedef unsigned short u16;
typedef short s16x8 __attribute__((ext_vector_type(8)));
typedef unsigned short u16x4 __attribute__((ext_vector_type(4)));
typedef __bf16 bf16x8 __attribute__((ext_vector_type(8)));
typedef float f32x4 __attribute__((ext_vector_type(4)));

__device__ __forceinline__ u16 f2bf(float f) {
  uint32_t u = __builtin_bit_cast(uint32_t, f);
  u += 0x7fffu + ((u >> 16) & 1u);
  return (u16)(u >> 16);
}
__device__ __forceinline__ float bf2f(u16 h) {
  uint32_t u = ((uint32_t)h) << 16;
  return __builtin_bit_cast(float, u);
}

// async global->LDS, 16B per lane; LDS dest = wave-uniform base + lane*16
__device__ __forceinline__ void gl16(const u16* g, u16* l) {
  __builtin_amdgcn_global_load_lds((const __attribute__((address_space(1))) void*)g,
                                   (__attribute__((address_space(3))) void*)l,
                                   16, 0, 0);
}

#define BARRIER() asm volatile("s_barrier" ::: "memory")

// ---------------- fp32 -> bf16 convert (8 elems/thread) ----------------
__global__ void k_convert(const float* __restrict__ in, u16* __restrict__ out, int n8) {
  int i = blockIdx.x * 256 + threadIdx.x;
  if (i >= n8) return;
  float4 a = ((const float4*)in)[2 * i];
  float4 b = ((const float4*)in)[2 * i + 1];
  s16x8 r;
  r[0] = (short)f2bf(a.x); r[1] = (short)f2bf(a.y);
  r[2] = (short)f2bf(a.z); r[3] = (short)f2bf(a.w);
  r[4] = (short)f2bf(b.x); r[5] = (short)f2bf(b.y);
  r[6] = (short)f2bf(b.z); r[7] = (short)f2bf(b.w);
  ((s16x8*)out)[i] = r;
}

__global__ void k_zero(int* __restrict__ counts) {
  if (threadIdx.x < NEXP) counts[threadIdx.x] = 0;
}

// ---------------- router: 4 waves/token, 2 experts/wave, fused x->bf16 ----------------
__global__ void k_router(const float* __restrict__ x, const float* __restrict__ gw,
                         u16* __restrict__ xb,
                         float* __restrict__ tkw, int* __restrict__ tki,
                         int* __restrict__ counts) {
  __shared__ double sm[NEXP];
  int t = blockIdx.x;
  int tid = threadIdx.x;
  int lane = tid & 63, wv = tid >> 6;     // 4 waves
  const float4* xr = (const float4*)(x + (size_t)t * DMODEL);
  const float4* gr = (const float4*)gw;
  int e0 = wv * 2, e1 = e0 + 1;
  double a0 = 0.0, a1 = 0.0;
#pragma unroll
  for (int it = 0; it < DMODEL / 4 / 64; ++it) {   // 8 iters
    int idx = it * 64 + lane;
    float4 xv = xr[idx];
    float4 g0 = gr[e0 * (DMODEL / 4) + idx];
    float4 g1 = gr[e1 * (DMODEL / 4) + idx];
    a0 += (double)xv.x * g0.x + (double)xv.y * g0.y +
          (double)xv.z * g0.z + (double)xv.w * g0.w;
    a1 += (double)xv.x * g1.x + (double)xv.y * g1.y +
          (double)xv.z * g1.z + (double)xv.w * g1.w;
    if (wv == 0) {   // fused x -> bf16 (wave 0 only)
      u16x4 r = { f2bf(xv.x), f2bf(xv.y), f2bf(xv.z), f2bf(xv.w) };
      ((u16x4*)(xb + (size_t)t * DMODEL))[idx] = r;
    }
  }
#pragma unroll
  for (int off = 32; off; off >>= 1) {
    a0 += __shfl_down(a0, off, 64);
    a1 += __shfl_down(a1, off, 64);
  }
  if (lane == 0) { sm[e0] = a0; sm[e1] = a1; }
  __syncthreads();
  if (tid == 0) {
    double acc[NEXP];
#pragma unroll
    for (int e = 0; e < NEXP; ++e) acc[e] = sm[e];
    int i0 = 0; double v0 = acc[0];
    for (int e = 1; e < NEXP; ++e) if (acc[e] > v0) { v0 = acc[e]; i0 = e; }
    int i1 = -1; double v1 = -1e300;
    for (int e = 0; e < NEXP; ++e) if (e != i0 && acc[e] > v1) { v1 = acc[e]; i1 = e; }
    double r = exp(v1 - v0);
    float w0 = (float)(1.0 / (1.0 + r));
    float w1 = 1.0f - w0;
    tkw[2 * t] = w0; tkw[2 * t + 1] = w1;
    tki[2 * t] = i0; tki[2 * t + 1] = i1;
    atomicAdd(&counts[i0], 1);
    atomicAdd(&counts[i1], 1);
  }
}

__global__ void k_scan(const int* __restrict__ counts, int* __restrict__ offs,
                       int* __restrict__ cursor) {
  if (threadIdx.x == 0) {
    int s = 0;
    for (int e = 0; e < NEXP; ++e) { offs[e] = s; cursor[e] = s; s += counts[e]; }
    offs[NEXP] = s;
  }
}

__global__ void k_assign(const int* __restrict__ tki, int* __restrict__ cursor,
                         int* __restrict__ pos, int* __restrict__ slot_tok) {
  int t = blockIdx.x * 256 + threadIdx.x;
  if (t >= T_TOK) return;
#pragma unroll
  for (int k = 0; k < 2; ++k) {
    int e = tki[2 * t + k];
    int p = atomicAdd(&cursor[e], 1);
    pos[2 * t + k] = p;
    slot_tok[p] = t;
  }
}

// ---------------- schedule table builder (deterministic) ----------------
// desc: bit31 = shared flag, bits24-27 = expert, bits12-23 = mb, bits0-11 = nb.
// Shared entries FIRST (LPT for DOWN: shared-down blocks have 2x the K).
__global__ void k_sched(const int* __restrict__ counts, int* __restrict__ tblGU,
                        int* __restrict__ tblDN, int* __restrict__ nact) {
  if (threadIdx.x != 0 || blockIdx.x != 0) return;
  int g = 0, d = 0;
  for (int m = 0; m < T_TOK / 256; ++m) {
    for (int nb = 0; nb < DFFS * 2 / 256; ++nb)
      tblGU[g++] = (int)(0x80000000u | (m << 12) | nb);
    for (int nb = 0; nb < DMODEL / 256; ++nb)
      tblDN[d++] = (int)(0x80000000u | (m << 12) | nb);
  }
  for (int e = 0; e < NEXP; ++e) {
    int mb = (counts[e] + 255) >> 8;
    for (int m = 0; m < mb; ++m) {
      for (int nb = 0; nb < DFF * 2 / 256; ++nb)
        tblGU[g++] = (e << 24) | (m << 12) | nb;
      for (int nb = 0; nb < DMODEL / 256; ++nb)
        tblDN[d++] = (e << 24) | (m << 12) | nb;
    }
  }
  nact[0] = g; nact[1] = d;
}

// ---------------- 256x256 NT bf16 GEMM, derived-wait 4-phase pipeline ----------------
// Schedule-table driven: PHASE 0 = merged routed+shared gate/up (K=2048, dual-B),
// PHASE 1 = merged routed+shared down (runtime K = 1408/2816).
// 512 threads = 8 waves (2M x 4N). BK=64. LDS: 2 dbuf x (A+B 256x64) = 128 KiB,
// XOR-swizzled (T2). Per K-tile: 4 phases, derived vmcnt(4)/vmcnt(6), setprio.
template <int PHASE>
__launch_bounds__(512, 2)
__global__ void k_gemm8(const int* __restrict__ tbl, const int* __restrict__ nact,
                        const u16* __restrict__ xb,
                        const u16* __restrict__ hr, const u16* __restrict__ hs,
                        const u16* __restrict__ wbg, const u16* __restrict__ wbu,
                        const u16* __restrict__ wbd,
                        const u16* __restrict__ wbsg, const u16* __restrict__ wbsu,
                        const u16* __restrict__ wbsd,
                        u16* __restrict__ P1r, u16* __restrict__ P2r,
                        u16* __restrict__ P1s, u16* __restrict__ P2s,
                        u16* __restrict__ yr, float* __restrict__ out,
                        const int* __restrict__ offs, const int* __restrict__ counts,
                        const int* __restrict__ slot_tok) {
  __shared__ __attribute__((aligned(16))) u16 lds[2 * 32768];  // 128 KiB

  if ((int)blockIdx.x >= nact[PHASE]) return;
  const int desc = tbl[blockIdx.x];
  const bool shrd = desc < 0;
  const int e = (desc >> 24) & 0xF;
  const int m0 = ((desc >> 12) & 0xFFF) * 256;
  const int n0 = (desc & 0xFFF) * 256;

  const u16 *A, *B1, *B2;
  u16 *C1, *C2;
  float* OF = nullptr;
  int base, cnt, nsplit, K;
  bool gather = false;
  if constexpr (PHASE == 0) {
    K = DMODEL;
    if (shrd) {
      A = xb; base = 0; cnt = T_TOK;
      B1 = wbsg; B2 = wbsu; C1 = P1s; C2 = P2s; nsplit = DFFS;
    } else {
      A = xb; gather = true; base = offs[e]; cnt = counts[e];
      size_t es = (size_t)e * DFF * DMODEL;
      B1 = wbg + es; B2 = wbu + es; C1 = P1r; C2 = P2r; nsplit = DFF;
    }
  } else {
    nsplit = DMODEL;
    if (shrd) {
      A = hs; base = 0; cnt = T_TOK; K = DFFS;
      B1 = B2 = wbsd; OF = out; C1 = C2 = nullptr;
    } else {
      A = hr; base = offs[e]; cnt = counts[e]; K = DFF;
      B1 = B2 = wbd + (size_t)e * DMODEL * DFF; C1 = C2 = yr;
    }
  }
  const int NT = K >> 6;

  int tid = threadIdx.x;
  int lane = tid & 63, wv = tid >> 6;
  int wm = wv >> 2, wn = wv & 3;
  int fr = lane & 15, fq = lane >> 4;

  // --- staging source pointers: 4 A-slabs + 4 B-slabs (64 rows each)
  int srow = tid >> 3;                     // wv*8 + (lane>>3), 0..63
  int sslot = (tid & 7) ^ (srow & 7);      // T2 pre-swizzle (involution)
  const u16* ap[4]; const u16* bp[4];
#pragma unroll
  for (int h = 0; h < 4; ++h) {
    int r = h * 64 + srow;                 // tile row 0..255
    int ra = m0 + r; ra = ra < cnt ? ra : cnt - 1;
    int ga = gather ? slot_tok[base + ra] : base + ra;
    ap[h] = A + (size_t)ga * K + sslot * 8;
    int nc = n0 + r;
    const u16* bb = (nc >= nsplit) ? (B2 + (size_t)(nc - nsplit) * K)
                                   : (B1 + (size_t)nc * K);
    bp[h] = bb + sslot * 8;
  }

#define STG_A(h, bufi, kt) gl16(ap[h] + (size_t)(kt) * 64, \
                                lds + (bufi) * 32768 + (h) * 4096 + wv * 512)
#define STG_B(h, bufi, kt) gl16(bp[h] + (size_t)(kt) * 64, \
                                lds + (bufi) * 32768 + 16384 + (h) * 4096 + wv * 512)

  // --- read bases (u16 units); swizzled k-slot is lane-constant per ks
  int sKs0 = ((0 + fq) ^ (fr & 7)) * 8;
  int sKs1 = ((4 + fq) ^ (fr & 7)) * 8;
  int aBase = wm * 8192 + fr * 64;                                   // + i*1024
  int bBase = 16384 + (wn >> 1) * 8192 + ((wn & 1) * 64 + fr) * 64;  // + j*1024

  f32x4 acc[8][4];
#pragma unroll
  for (int i = 0; i < 8; ++i)
#pragma unroll
    for (int j = 0; j < 4; ++j) acc[i][j] = (f32x4){0.f, 0.f, 0.f, 0.f};

  // prologue: tile0 pairs [A02, B01, B23, A13], then A02 of tile1
  STG_A(0, 0, 0); STG_A(2, 0, 0);
  STG_B(0, 0, 0); STG_B(1, 0, 0);
  STG_B(2, 0, 0); STG_B(3, 0, 0);
  STG_A(1, 0, 0); STG_A(3, 0, 0);
  STG_A(0, 1, 1); STG_A(2, 1, 1);

  bf16x8 af[4][2], bkA[2][2], bkB[2][2];
  for (int t = 0; t < NT; ++t) {
    const int buf = t & 1, nbuf = buf ^ 1;
    const u16* lbuf = lds + buf * 32768;
    const bool hn1 = (t + 1) < NT, hn2 = (t + 2) < NT;

    // ---------- phase 1: (mq0, nq0) ----------
    if (t == NT - 1) asm volatile("s_waitcnt vmcnt(2)" ::: "memory");
    else             asm volatile("s_waitcnt vmcnt(4)" ::: "memory");
    BARRIER();
    __builtin_amdgcn_sched_barrier(0);
#pragma unroll
    for (int il = 0; il < 4; ++il) {
      af[il][0] = *(const bf16x8*)(lbuf + aBase + il * 1024 + sKs0);
      af[il][1] = *(const bf16x8*)(lbuf + aBase + il * 1024 + sKs1);
    }
#pragma unroll
    for (int jl = 0; jl < 2; ++jl) {
      bkA[jl][0] = *(const bf16x8*)(lbuf + bBase + jl * 1024 + sKs0);
      bkA[jl][1] = *(const bf16x8*)(lbuf + bBase + jl * 1024 + sKs1);
    }
    if (hn1) { STG_B(0, nbuf, t + 1); STG_B(1, nbuf, t + 1); }
    asm volatile("s_waitcnt lgkmcnt(0)" ::: "memory");
    __builtin_amdgcn_sched_barrier(0);
    __builtin_amdgcn_s_setprio(1);
#pragma unroll
    for (int il = 0; il < 4; ++il)
#pragma unroll
      for (int jl = 0; jl < 2; ++jl) {
        acc[il][jl] = __builtin_amdgcn_mfma_f32_16x16x32_bf16(af[il][0], bkA[jl][0], acc[il][jl], 0, 0, 0);
        acc[il][jl] = __builtin_amdgcn_mfma_f32_16x16x32_bf16(af[il][1], bkA[jl][1], acc[il][jl], 0, 0, 0);
      }
    __builtin_amdgcn_s_setprio(0);
    __builtin_amdgcn_sched_barrier(0);

    // ---------- phase 2: (mq0, nq1) ----------
    BARRIER();
    __builtin_amdgcn_sched_barrier(0);
#pragma unroll
    for (int jl = 0; jl < 2; ++jl) {
      bkB[jl][0] = *(const bf16x8*)(lbuf + bBase + (2 + jl) * 1024 + sKs0);
      bkB[jl][1] = *(const bf16x8*)(lbuf + bBase + (2 + jl) * 1024 + sKs1);
    }
    if (hn1) { STG_B(2, nbuf, t + 1); STG_B(3, nbuf, t + 1); }
    asm volatile("s_waitcnt lgkmcnt(0)" ::: "memory");
    __builtin_amdgcn_sched_barrier(0);
    __builtin_amdgcn_s_setprio(1);
#pragma unroll
    for (int il = 0; il < 4; ++il)
#pragma unroll
      for (int jl = 0; jl < 2; ++jl) {
        acc[il][2 + jl] = __builtin_amdgcn_mfma_f32_16x16x32_bf16(af[il][0], bkB[jl][0], acc[il][2 + jl], 0, 0, 0);
        acc[il][2 + jl] = __builtin_amdgcn_mfma_f32_16x16x32_bf16(af[il][1], bkB[jl][1], acc[il][2 + jl], 0, 0, 0);
      }
    __builtin_amdgcn_s_setprio(0);
    __builtin_amdgcn_sched_barrier(0);

    // ---------- phase 3: (mq1, nq0) ----------
    if (t == NT - 1) asm volatile("s_waitcnt vmcnt(0)" ::: "memory");
    else             asm volatile("s_waitcnt vmcnt(6)" ::: "memory");
    BARRIER();
    __builtin_amdgcn_sched_barrier(0);
#pragma unroll
    for (int il = 0; il < 4; ++il) {
      af[il][0] = *(const bf16x8*)(lbuf + aBase + (4 + il) * 1024 + sKs0);
      af[il][1] = *(const bf16x8*)(lbuf + aBase + (4 + il) * 1024 + sKs1);
    }
    if (hn1) { STG_A(1, nbuf, t + 1); STG_A(3, nbuf, t + 1); }
    asm volatile("s_waitcnt lgkmcnt(0)" ::: "memory");
    __builtin_amdgcn_sched_barrier(0);
    __builtin_amdgcn_s_setprio(1);
#pragma unroll
    for (int il = 0; il < 4; ++il)
#pragma unroll
      for (int jl = 0; jl < 2; ++jl) {
        acc[4 + il][jl] = __builtin_amdgcn_mfma_f32_16x16x32_bf16(af[il][0], bkA[jl][0], acc[4 + il][jl], 0, 0, 0);
        acc[4 + il][jl] = __builtin_amdgcn_mfma_f32_16x16x32_bf16(af[il][1], bkA[jl][1], acc[4 + il][jl], 0, 0, 0);
      }
    __builtin_amdgcn_s_setprio(0);
    __builtin_amdgcn_sched_barrier(0);

    // ---------- phase 4: (mq1, nq1) ----------
    BARRIER();
    __builtin_amdgcn_sched_barrier(0);
#pragma unroll
    for (int jl = 0; jl < 2; ++jl) {
      bkB[jl][0] = *(const bf16x8*)(lbuf + bBase + (2 + jl) * 1024 + sKs0);
      bkB[jl][1] = *(const bf16x8*)(lbuf + bBase + (2 + jl) * 1024 + sKs1);
    }
    if (hn2) { STG_A(0, buf, t + 2); STG_A(2, buf, t + 2); }  // A02 of buf dead since p2
    asm volatile("s_waitcnt lgkmcnt(0)" ::: "memory");
    __builtin_amdgcn_sched_barrier(0);
    __builtin_amdgcn_s_setprio(1);
#pragma unroll
    for (int il = 0; il < 4; ++il)
#pragma unroll
      for (int jl = 0; jl < 2; ++jl) {
        acc[4 + il][2 + jl] = __builtin_amdgcn_mfma_f32_16x16x32_bf16(af[il][0], bkB[jl][0], acc[4 + il][2 + jl], 0, 0, 0);
        acc[4 + il][2 + jl] = __builtin_amdgcn_mfma_f32_16x16x32_bf16(af[il][1], bkB[jl][1], acc[4 + il][2 + jl], 0, 0, 0);
      }
    __builtin_amdgcn_s_setprio(0);
    __builtin_amdgcn_sched_barrier(0);
  }
#undef STG_A
#undef STG_B

  // --- epilogue ---
#pragma unroll
  for (int i = 0; i < 8; ++i) {
    int row_t = wm * 128 + i * 16 + fq * 4;
#pragma unroll
    for (int r = 0; r < 4; ++r) {
      int m = m0 + row_t + r;
      if (m >= cnt) continue;
      size_t rowoff = (size_t)(base + m) * (size_t)nsplit;
#pragma unroll
      for (int j = 0; j < 4; ++j) {
        int col_t = n0 + wn * 64 + j * 16 + fr;
        float v = acc[i][j][r];
        if (PHASE == 1 && shrd)      OF[rowoff + col_t] = v;
        else if (col_t >= nsplit)    C2[rowoff + col_t - nsplit] = f2bf(v);
        else                         C1[rowoff + col_t] = f2bf(v);
      }
    }
  }
}

// ---------------- merged h = silu(g) * u over two buffer pairs ----------------
__global__ void k_silu2(const u16* __restrict__ g1, const u16* __restrict__ u1,
                        u16* __restrict__ h1, int n1,
                        const u16* __restrict__ g2, const u16* __restrict__ u2,
                        u16* __restrict__ h2, int n2) {
  int i = blockIdx.x * 256 + threadIdx.x;
  const u16 *g, *u; u16* h; int idx;
  if (i < n1) { g = g1; u = u1; h = h1; idx = i; }
  else { idx = i - n1; if (idx >= n2) return; g = g2; u = u2; h = h2; }
  s16x8 gv = ((const s16x8*)g)[idx];
  s16x8 uv = ((const s16x8*)u)[idx];
  s16x8 hv;
#pragma unroll
  for (int j = 0; j < 8; ++j) {
    float gf = bf2f((u16)gv[j]);
    float uf = bf2f((u16)uv[j]);
    float s = gf / (1.f + __expf(-gf));
    hv[j] = (short)f2bf(s * uf);
  }
  ((s16x8*)h)[idx] = hv;
}

// ---------------- y[t] += w0*yr[pos0] + w1*yr[pos1] ----------------
__global__ void k_combine(float* __restrict__ y, const u16* __restrict__ yr,
                          const float* __restrict__ tkw, const int* __restrict__ pos) {
  int t = blockIdx.x;
  int i = threadIdx.x;
  float w0 = tkw[2 * t], w1 = tkw[2 * t + 1];
  size_t p0 = (size_t)pos[2 * t] * DMODEL, p1 = (size_t)pos[2 * t + 1] * DMODEL;
  int d0 = i * 8;
  s16x8 a = *(const s16x8*)(yr + p0 + d0);
  s16x8 b = *(const s16x8*)(yr + p1 + d0);
  float* yo = y + (size_t)t * DMODEL + d0;
#pragma unroll
  for (int j = 0; j < 8; ++j)
    yo[j] += w0 * bf2f((u16)a[j]) + w1 * bf2f((u16)b[j]);
}

extern "C" void kernel_launch(void* const* d_in, const int* in_sizes, int n_in,
                              void* d_out, int out_size, void* d_ws, size_t ws_size,
                              hipStream_t stream) {
  const float* x   = (const float*)d_in[0];
  const float* gw  = (const float*)d_in[1];
  const float* wg  = (const float*)d_in[2];
  const float* wu  = (const float*)d_in[3];
  const float* wd  = (const float*)d_in[4];
  const float* wsg = (const float*)d_in[5];
  const float* wsu = (const float*)d_in[6];
  const float* wsd = (const float*)d_in[7];
  float* out = (float*)d_out;

  char* ws = (char*)d_ws;
  size_t o = 0;
  auto alloc = [&](size_t bytes) -> void* {
    void* p = ws + o;
    o += (bytes + 255) & ~(size_t)255;
    return p;
  };
  u16* xb   = (u16*)alloc((size_t)T_TOK * DMODEL * 2);
  u16* wbg  = (u16*)alloc((size_t)NEXP * DFF * DMODEL * 2);
  u16* wbu  = (u16*)alloc((size_t)NEXP * DFF * DMODEL * 2);
  u16* wbd  = (u16*)alloc((size_t)NEXP * DMODEL * DFF * 2);
  u16* wbsg = (u16*)alloc((size_t)DFFS * DMODEL * 2);
  u16* wbsu = (u16*)alloc((size_t)DFFS * DMODEL * 2);
  u16* wbsd = (u16*)alloc((size_t)DMODEL * DFFS * 2);
  u16* P1r  = (u16*)alloc((size_t)NSLOT * DFF * 2);    // 23.07 MB (g_r -> h_r)
  u16* P1s  = (u16*)alloc((size_t)T_TOK * DFFS * 2);   // 23.07 MB (g_s -> h_s)
  u16* P2r  = (u16*)alloc((size_t)NSLOT * DFF * 2);    // u_r; aliased by yr after silu
  u16* P2s  = (u16*)alloc((size_t)T_TOK * DFFS * 2);   // u_s; contiguous after P2r
  u16* yr   = P2r;  // alias: yr needs 33.6 MB <= P2r+P2s (46.1 MB); u_* dead by then
  float* tkw = (float*)alloc((size_t)T_TOK * 2 * 4);
  int* tki   = (int*)alloc((size_t)T_TOK * 2 * 4);
  int* pos   = (int*)alloc((size_t)T_TOK * 2 * 4);
  int* slot_tok = (int*)alloc((size_t)NSLOT * 4);
  int* counts   = (int*)alloc(64);
  int* offs     = (int*)alloc(64);
  int* cursor   = (int*)alloc(64);
  int* tblGU    = (int*)alloc(GU_GRID * 4);
  int* tblDN    = (int*)alloc(DN_GRID * 4);
  int* nact     = (int*)alloc(64);
  if (o > ws_size) {
    fprintf(stderr, "kernel_launch: ws too small: need %zu have %zu\n", o, ws_size);
    return;
  }

  // --- conversions fp32 -> bf16 (x conversion is fused into k_router) ---
  {
    int n8w = NEXP * DFF * DMODEL / 8;
    k_convert<<<(n8w + 255) / 256, 256, 0, stream>>>(wg, wbg, n8w);
    k_convert<<<(n8w + 255) / 256, 256, 0, stream>>>(wu, wbu, n8w);
    k_convert<<<(n8w + 255) / 256, 256, 0, stream>>>(wd, wbd, n8w);
    int n8s = DFFS * DMODEL / 8;
    k_convert<<<(n8s + 255) / 256, 256, 0, stream>>>(wsg, wbsg, n8s);
    k_convert<<<(n8s + 255) / 256, 256, 0, stream>>>(wsu, wbsu, n8s);
    k_convert<<<(n8s + 255) / 256, 256, 0, stream>>>(wsd, wbsd, n8s);
  }

  // --- routing (also produces xb) + schedule tables ---
  k_zero<<<1, 64, 0, stream>>>(counts);
  k_router<<<T_TOK, 256, 0, stream>>>(x, gw, xb, tkw, tki, counts);
  k_scan<<<1, 64, 0, stream>>>(counts, offs, cursor);
  k_assign<<<(T_TOK + 255) / 256, 256, 0, stream>>>(tki, cursor, pos, slot_tok);
  k_sched<<<1, 64, 0, stream>>>(counts, tblGU, tblDN, nact);

  // --- merged gate/up GEMM (routed + shared) ---
  k_gemm8<0><<<GU_GRID, 512, 0, stream>>>(
      tblGU, nact, xb, nullptr, nullptr,
      wbg, wbu, wbd, wbsg, wbsu, wbsd,
      P1r, P2r, P1s, P2s, yr, out, offs, counts, slot_tok);

  // --- merged silu ---
  {
    int n1 = NSLOT * DFF / 8, n2 = T_TOK * DFFS / 8;
    k_silu2<<<(n1 + n2 + 255) / 256, 256, 0, stream>>>(
        P1r, P2r, P1r, n1, P1s, P2s, P1s, n2);
  }

  // --- merged down GEMM (routed -> yr, shared -> out) ---
  k_gemm8<1><<<DN_GRID, 512, 0, stream>>>(
      tblDN, nact, xb, P1r, P1s,
      wbg, wbu, wbd, wbsg, wbsu, wbsd,
      P1r, P2r, P1s, P2s, yr, out, offs, counts, slot_tok);

  // --- combine routed into output ---
  k_combine<<<T_TOK, 256, 0, stream>>>(out, yr, tkw, pos);
}

// Round 7
// 584.666 us; speedup vs baseline: 1.3393x; 1.0098x over previous
//
#include <hip/hip_runtime.h>
#include <stdint.h>
#include <stdio.h>

#define T_TOK 4096
#define DMODEL 2048
#define NEXP 8
#define DFF 1408
#define DFFS 2816
#define NSLOT 8192   // T_TOK * 2

// schedule-table grid bounds (worst case): routed m-blocks sum <= 39
#define GU_GRID (16 * 22 + 39 * 11)   // 781
#define DN_GRID (16 * 8 + 39 * 8)     // 440

typedef unsigned short u16;
typedef short s16x8 __attribute__((ext_vector_type(8)));
typedef unsigned short u16x4 __attribute__((ext_vector_type(4)));
typedef __bf16 bf16x8 __attribute__((ext_vector_type(8)));
typedef float f32x4 __attribute__((ext_vector_type(4)));

__device__ __forceinline__ u16 f2bf(float f) {
  uint32_t u = __builtin_bit_cast(uint32_t, f);
  u += 0x7fffu + ((u >> 16) & 1u);
  return (u16)(u >> 16);
}
__device__ __forceinline__ float bf2f(u16 h) {
  uint32_t u = ((uint32_t)h) << 16;
  return __builtin_bit_cast(float, u);
}

// async global->LDS, 16B per lane; LDS dest = wave-uniform base + lane*16
__device__ __forceinline__ void gl16(const u16* g, u16* l) {
  __builtin_amdgcn_global_load_lds((const __attribute__((address_space(1))) void*)g,
                                   (__attribute__((address_space(3))) void*)l,
                                   16, 0, 0);
}

#define BARRIER() asm volatile("s_barrier" ::: "memory")

// ---------------- merged fp32 -> bf16 convert (grid-stride, 8 elems/iter) ----------------
__global__ void k_convert6(const float* __restrict__ s0, u16* __restrict__ d0, int n0,
                           const float* __restrict__ s1, u16* __restrict__ d1, int n1,
                           const float* __restrict__ s2, u16* __restrict__ d2, int n2,
                           const float* __restrict__ s3, u16* __restrict__ d3, int n3,
                           const float* __restrict__ s4, u16* __restrict__ d4, int n4,
                           const float* __restrict__ s5, u16* __restrict__ d5, int n5) {
  int total = n0 + n1 + n2 + n3 + n4 + n5;
  int stride = gridDim.x * 256;
  for (int i = blockIdx.x * 256 + threadIdx.x; i < total; i += stride) {
    const float* s; u16* d; int k = i;
    if (k < n0) { s = s0; d = d0; }
    else { k -= n0;
      if (k < n1) { s = s1; d = d1; }
      else { k -= n1;
        if (k < n2) { s = s2; d = d2; }
        else { k -= n2;
          if (k < n3) { s = s3; d = d3; }
          else { k -= n3;
            if (k < n4) { s = s4; d = d4; }
            else { k -= n4; s = s5; d = d5; }
          }
        }
      }
    }
    float4 a = ((const float4*)s)[2 * k];
    float4 b = ((const float4*)s)[2 * k + 1];
    s16x8 r;
    r[0] = (short)f2bf(a.x); r[1] = (short)f2bf(a.y);
    r[2] = (short)f2bf(a.z); r[3] = (short)f2bf(a.w);
    r[4] = (short)f2bf(b.x); r[5] = (short)f2bf(b.y);
    r[6] = (short)f2bf(b.z); r[7] = (short)f2bf(b.w);
    ((s16x8*)d)[k] = r;
  }
}

__global__ void k_zero(int* __restrict__ counts) {
  if (threadIdx.x < NEXP) counts[threadIdx.x] = 0;
}

// ---------------- router: 4 waves/token, 2 experts/wave, fused x->bf16 ----------------
__global__ void k_router(const float* __restrict__ x, const float* __restrict__ gw,
                         u16* __restrict__ xb,
                         float* __restrict__ tkw, int* __restrict__ tki,
                         int* __restrict__ counts) {
  __shared__ double sm[NEXP];
  int t = blockIdx.x;
  int tid = threadIdx.x;
  int lane = tid & 63, wv = tid >> 6;     // 4 waves
  const float4* xr = (const float4*)(x + (size_t)t * DMODEL);
  const float4* gr = (const float4*)gw;
  int e0 = wv * 2, e1 = e0 + 1;
  double a0 = 0.0, a1 = 0.0;
#pragma unroll
  for (int it = 0; it < DMODEL / 4 / 64; ++it) {   // 8 iters
    int idx = it * 64 + lane;
    float4 xv = xr[idx];
    float4 g0 = gr[e0 * (DMODEL / 4) + idx];
    float4 g1 = gr[e1 * (DMODEL / 4) + idx];
    a0 += (double)xv.x * g0.x + (double)xv.y * g0.y +
          (double)xv.z * g0.z + (double)xv.w * g0.w;
    a1 += (double)xv.x * g1.x + (double)xv.y * g1.y +
          (double)xv.z * g1.z + (double)xv.w * g1.w;
    if (wv == 0) {   // fused x -> bf16 (wave 0 only)
      u16x4 r = { f2bf(xv.x), f2bf(xv.y), f2bf(xv.z), f2bf(xv.w) };
      ((u16x4*)(xb + (size_t)t * DMODEL))[idx] = r;
    }
  }
#pragma unroll
  for (int off = 32; off; off >>= 1) {
    a0 += __shfl_down(a0, off, 64);
    a1 += __shfl_down(a1, off, 64);
  }
  if (lane == 0) { sm[e0] = a0; sm[e1] = a1; }
  __syncthreads();
  if (tid == 0) {
    double acc[NEXP];
#pragma unroll
    for (int e = 0; e < NEXP; ++e) acc[e] = sm[e];
    int i0 = 0; double v0 = acc[0];
    for (int e = 1; e < NEXP; ++e) if (acc[e] > v0) { v0 = acc[e]; i0 = e; }
    int i1 = -1; double v1 = -1e300;
    for (int e = 0; e < NEXP; ++e) if (e != i0 && acc[e] > v1) { v1 = acc[e]; i1 = e; }
    double r = exp(v1 - v0);
    float w0 = (float)(1.0 / (1.0 + r));
    float w1 = 1.0f - w0;
    tkw[2 * t] = w0; tkw[2 * t + 1] = w1;
    tki[2 * t] = i0; tki[2 * t + 1] = i1;
    atomicAdd(&counts[i0], 1);
    atomicAdd(&counts[i1], 1);
  }
}

// ---------------- merged scan + schedule-table builder ----------------
// desc: bit31 = shared flag, bits24-27 = expert, bits12-23 = mb, bits0-11 = nb.
// Shared entries FIRST (LPT for DOWN: shared-down blocks have 2x the K).
__global__ void k_scan_sched(const int* __restrict__ counts, int* __restrict__ offs,
                             int* __restrict__ cursor, int* __restrict__ tblGU,
                             int* __restrict__ tblDN, int* __restrict__ nact) {
  if (threadIdx.x != 0 || blockIdx.x != 0) return;
  int s = 0;
  for (int e = 0; e < NEXP; ++e) { offs[e] = s; cursor[e] = s; s += counts[e]; }
  offs[NEXP] = s;
  int g = 0, d = 0;
  for (int m = 0; m < T_TOK / 256; ++m) {
    for (int nb = 0; nb < DFFS * 2 / 256; ++nb)
      tblGU[g++] = (int)(0x80000000u | (m << 12) | nb);
    for (int nb = 0; nb < DMODEL / 256; ++nb)
      tblDN[d++] = (int)(0x80000000u | (m << 12) | nb);
  }
  for (int e = 0; e < NEXP; ++e) {
    int mb = (counts[e] + 255) >> 8;
    for (int m = 0; m < mb; ++m) {
      for (int nb = 0; nb < DFF * 2 / 256; ++nb)
        tblGU[g++] = (e << 24) | (m << 12) | nb;
      for (int nb = 0; nb < DMODEL / 256; ++nb)
        tblDN[d++] = (e << 24) | (m << 12) | nb;
    }
  }
  nact[0] = g; nact[1] = d;
}

__global__ void k_assign(const int* __restrict__ tki, int* __restrict__ cursor,
                         int* __restrict__ pos, int* __restrict__ slot_tok) {
  int t = blockIdx.x * 256 + threadIdx.x;
  if (t >= T_TOK) return;
#pragma unroll
  for (int k = 0; k < 2; ++k) {
    int e = tki[2 * t + k];
    int p = atomicAdd(&cursor[e], 1);
    pos[2 * t + k] = p;
    slot_tok[p] = t;
  }
}

// ---------------- 256x256 NT bf16 GEMM, reads-lead-one-phase pipeline ----------------
// Schedule-table driven: PHASE 0 = merged gate/up (K=2048, dual-B),
// PHASE 1 = merged down (runtime K = 1408/2816).
// 512 thr = 8 waves (2M x 4N), BK=64, LDS 2 x 64KB dbuf, T2 XOR-swizzle.
// Per tile t (buffers by parity): ds_reads for phase p+1 issue before phase p's
// MFMA; 2 barriers/tile. A-slabs of tile X staged at X-2.s2/s3, B-slabs at
// X-1.s0/s1. s2-top: lgkmcnt(0)+barrier (frees read buffer for staging).
// s3-top: vmcnt(2|0)+barrier (next tile fully staged), then read next A02/B01.
template <int PHASE>
__launch_bounds__(512, 2)
__global__ void k_gemm8(const int* __restrict__ tbl, const int* __restrict__ nact,
                        const u16* __restrict__ xb,
                        const u16* __restrict__ hr, const u16* __restrict__ hs,
                        const u16* __restrict__ wbg, const u16* __restrict__ wbu,
                        const u16* __restrict__ wbd,
                        const u16* __restrict__ wbsg, const u16* __restrict__ wbsu,
                        const u16* __restrict__ wbsd,
                        u16* __restrict__ P1r, u16* __restrict__ P2r,
                        u16* __restrict__ P1s, u16* __restrict__ P2s,
                        u16* __restrict__ yr, float* __restrict__ out,
                        const int* __restrict__ offs, const int* __restrict__ counts,
                        const int* __restrict__ slot_tok) {
  __shared__ __attribute__((aligned(16))) u16 lds[2 * 32768];  // 128 KiB

  if ((int)blockIdx.x >= nact[PHASE]) return;
  const int desc = tbl[blockIdx.x];
  const bool shrd = desc < 0;
  const int e = (desc >> 24) & 0xF;
  const int m0 = ((desc >> 12) & 0xFFF) * 256;
  const int n0 = (desc & 0xFFF) * 256;

  const u16 *A, *B1, *B2;
  u16 *C1, *C2;
  float* OF = nullptr;
  int base, cnt, nsplit, K;
  bool gather = false;
  if constexpr (PHASE == 0) {
    K = DMODEL;
    if (shrd) {
      A = xb; base = 0; cnt = T_TOK;
      B1 = wbsg; B2 = wbsu; C1 = P1s; C2 = P2s; nsplit = DFFS;
    } else {
      A = xb; gather = true; base = offs[e]; cnt = counts[e];
      size_t es = (size_t)e * DFF * DMODEL;
      B1 = wbg + es; B2 = wbu + es; C1 = P1r; C2 = P2r; nsplit = DFF;
    }
  } else {
    nsplit = DMODEL;
    if (shrd) {
      A = hs; base = 0; cnt = T_TOK; K = DFFS;
      B1 = B2 = wbsd; OF = out; C1 = C2 = nullptr;
    } else {
      A = hr; base = offs[e]; cnt = counts[e]; K = DFF;
      B1 = B2 = wbd + (size_t)e * DMODEL * DFF; C1 = C2 = yr;
    }
  }
  const int NT = K >> 6;

  int tid = threadIdx.x;
  int lane = tid & 63, wv = tid >> 6;
  int wm = wv >> 2, wn = wv & 3;
  int fr = lane & 15, fq = lane >> 4;

  // --- staging source pointers: 4 A-slabs + 4 B-slabs (64 rows each)
  int srow = tid >> 3;                     // wv*8 + (lane>>3), 0..63
  int sslot = (tid & 7) ^ (srow & 7);      // T2 pre-swizzle (involution)
  const u16* ap[4]; const u16* bp[4];
#pragma unroll
  for (int h = 0; h < 4; ++h) {
    int r = h * 64 + srow;                 // tile row 0..255
    int ra = m0 + r; ra = ra < cnt ? ra : cnt - 1;
    int ga = gather ? slot_tok[base + ra] : base + ra;
    ap[h] = A + (size_t)ga * K + sslot * 8;
    int nc = n0 + r;
    const u16* bb = (nc >= nsplit) ? (B2 + (size_t)(nc - nsplit) * K)
                                   : (B1 + (size_t)nc * K);
    bp[h] = bb + sslot * 8;
  }

#define STG_A(h, bufi, kt) gl16(ap[h] + (size_t)(kt) * 64, \
                                lds + (bufi) * 32768 + (h) * 4096 + wv * 512)
#define STG_B(h, bufi, kt) gl16(bp[h] + (size_t)(kt) * 64, \
                                lds + (bufi) * 32768 + 16384 + (h) * 4096 + wv * 512)

  // --- read bases (u16 units); swizzled k-slot is lane-constant per ks
  int sKs0 = ((0 + fq) ^ (fr & 7)) * 8;
  int sKs1 = ((4 + fq) ^ (fr & 7)) * 8;
  int aBase = wm * 8192 + fr * 64;                                   // + i*1024
  int bBase = 16384 + (wn >> 1) * 8192 + ((wn & 1) * 64 + fr) * 64;  // + j*1024

  f32x4 acc[8][4];
#pragma unroll
  for (int i = 0; i < 8; ++i)
#pragma unroll
    for (int j = 0; j < 4; ++j) acc[i][j] = (f32x4){0.f, 0.f, 0.f, 0.f};

  // prologue: full tile0 + A-slabs of tile1
  STG_A(0, 0, 0); STG_A(1, 0, 0); STG_A(2, 0, 0); STG_A(3, 0, 0);
  STG_B(0, 0, 0); STG_B(1, 0, 0); STG_B(2, 0, 0); STG_B(3, 0, 0);
  if (NT > 1) { STG_A(0, 1, 1); STG_A(1, 1, 1); STG_A(2, 1, 1); STG_A(3, 1, 1); }
  if (NT > 1) asm volatile("s_waitcnt vmcnt(4)" ::: "memory");
  else        asm volatile("s_waitcnt vmcnt(0)" ::: "memory");
  BARRIER();
  __builtin_amdgcn_sched_barrier(0);

  bf16x8 rAa[4][2], rAb[4][2], rB01[2][2], rB23[2][2];
#pragma unroll
  for (int il = 0; il < 4; ++il) {
    rAa[il][0] = *(const bf16x8*)(lds + aBase + il * 1024 + sKs0);
    rAa[il][1] = *(const bf16x8*)(lds + aBase + il * 1024 + sKs1);
  }
#pragma unroll
  for (int jl = 0; jl < 2; ++jl) {
    rB01[jl][0] = *(const bf16x8*)(lds + bBase + jl * 1024 + sKs0);
    rB01[jl][1] = *(const bf16x8*)(lds + bBase + jl * 1024 + sKs1);
  }

  for (int t = 0; t < NT; ++t) {
    const int buf = t & 1, nbuf = buf ^ 1;
    const u16* lbuf = lds + buf * 32768;
    const u16* lbufN = lds + nbuf * 32768;
    const bool hn1 = (t + 1) < NT, hn2 = (t + 2) < NT;

    // ---- s0: read B23(t); stage B0,B1(t+1)->nbuf; MFMA mq0 x nq0
#pragma unroll
    for (int jl = 0; jl < 2; ++jl) {
      rB23[jl][0] = *(const bf16x8*)(lbuf + bBase + (2 + jl) * 1024 + sKs0);
      rB23[jl][1] = *(const bf16x8*)(lbuf + bBase + (2 + jl) * 1024 + sKs1);
    }
    if (hn1) { STG_B(0, nbuf, t + 1); STG_B(1, nbuf, t + 1); }
    __builtin_amdgcn_s_setprio(1);
#pragma unroll
    for (int il = 0; il < 4; ++il)
#pragma unroll
      for (int jl = 0; jl < 2; ++jl) {
        acc[il][jl] = __builtin_amdgcn_mfma_f32_16x16x32_bf16(rAa[il][0], rB01[jl][0], acc[il][jl], 0, 0, 0);
        acc[il][jl] = __builtin_amdgcn_mfma_f32_16x16x32_bf16(rAa[il][1], rB01[jl][1], acc[il][jl], 0, 0, 0);
      }
    __builtin_amdgcn_s_setprio(0);

    // ---- s1: read A13(t); stage B2,B3(t+1)->nbuf; MFMA mq0 x nq1
#pragma unroll
    for (int il = 0; il < 4; ++il) {
      rAb[il][0] = *(const bf16x8*)(lbuf + aBase + (4 + il) * 1024 + sKs0);
      rAb[il][1] = *(const bf16x8*)(lbuf + aBase + (4 + il) * 1024 + sKs1);
    }
    if (hn1) { STG_B(2, nbuf, t + 1); STG_B(3, nbuf, t + 1); }
    __builtin_amdgcn_s_setprio(1);
#pragma unroll
    for (int il = 0; il < 4; ++il)
#pragma unroll
      for (int jl = 0; jl < 2; ++jl) {
        acc[il][2 + jl] = __builtin_amdgcn_mfma_f32_16x16x32_bf16(rAa[il][0], rB23[jl][0], acc[il][2 + jl], 0, 0, 0);
        acc[il][2 + jl] = __builtin_amdgcn_mfma_f32_16x16x32_bf16(rAa[il][1], rB23[jl][1], acc[il][2 + jl], 0, 0, 0);
      }
    __builtin_amdgcn_s_setprio(0);

    // ---- s2: drain reads + barrier (frees buf for t+2 A-stages); MFMA mq1 x nq0
    asm volatile("s_waitcnt lgkmcnt(0)" ::: "memory");
    BARRIER();
    __builtin_amdgcn_sched_barrier(0);
    if (hn2) { STG_A(0, buf, t + 2); STG_A(1, buf, t + 2); }
    __builtin_amdgcn_s_setprio(1);
#pragma unroll
    for (int il = 0; il < 4; ++il)
#pragma unroll
      for (int jl = 0; jl < 2; ++jl) {
        acc[4 + il][jl] = __builtin_amdgcn_mfma_f32_16x16x32_bf16(rAb[il][0], rB01[jl][0], acc[4 + il][jl], 0, 0, 0);
        acc[4 + il][jl] = __builtin_amdgcn_mfma_f32_16x16x32_bf16(rAb[il][1], rB01[jl][1], acc[4 + il][jl], 0, 0, 0);
      }
    __builtin_amdgcn_s_setprio(0);

    // ---- s3: vmcnt+barrier (t+1 fully staged); stage A2,A3(t+2); read A02/B01(t+1); MFMA mq1 x nq1
    if (hn1) {
      if (hn2) asm volatile("s_waitcnt vmcnt(2)" ::: "memory");
      else     asm volatile("s_waitcnt vmcnt(0)" ::: "memory");
      BARRIER();
      __builtin_amdgcn_sched_barrier(0);
      if (hn2) { STG_A(2, buf, t + 2); STG_A(3, buf, t + 2); }
#pragma unroll
      for (int il = 0; il < 4; ++il) {
        rAa[il][0] = *(const bf16x8*)(lbufN + aBase + il * 1024 + sKs0);
        rAa[il][1] = *(const bf16x8*)(lbufN + aBase + il * 1024 + sKs1);
      }
#pragma unroll
      for (int jl = 0; jl < 2; ++jl) {
        rB01[jl][0] = *(const bf16x8*)(lbufN + bBase + jl * 1024 + sKs0);
        rB01[jl][1] = *(const bf16x8*)(lbufN + bBase + jl * 1024 + sKs1);
      }
    }
    __builtin_amdgcn_s_setprio(1);
#pragma unroll
    for (int il = 0; il < 4; ++il)
#pragma unroll
      for (int jl = 0; jl < 2; ++jl) {
        acc[4 + il][2 + jl] = __builtin_amdgcn_mfma_f32_16x16x32_bf16(rAb[il][0], rB23[jl][0], acc[4 + il][2 + jl], 0, 0, 0);
        acc[4 + il][2 + jl] = __builtin_amdgcn_mfma_f32_16x16x32_bf16(rAb[il][1], rB23[jl][1], acc[4 + il][2 + jl], 0, 0, 0);
      }
    __builtin_amdgcn_s_setprio(0);
  }
#undef STG_A
#undef STG_B

  // --- epilogue ---
#pragma unroll
  for (int i = 0; i < 8; ++i) {
    int row_t = wm * 128 + i * 16 + fq * 4;
#pragma unroll
    for (int r = 0; r < 4; ++r) {
      int m = m0 + row_t + r;
      if (m >= cnt) continue;
      size_t rowoff = (size_t)(base + m) * (size_t)nsplit;
#pragma unroll
      for (int j = 0; j < 4; ++j) {
        int col_t = n0 + wn * 64 + j * 16 + fr;
        float v = acc[i][j][r];
        if (PHASE == 1 && shrd)      OF[rowoff + col_t] = v;
        else if (col_t >= nsplit)    C2[rowoff + col_t - nsplit] = f2bf(v);
        else                         C1[rowoff + col_t] = f2bf(v);
      }
    }
  }
}

// ---------------- merged h = silu(g) * u over two buffer pairs ----------------
__global__ void k_silu2(const u16* __restrict__ g1, const u16* __restrict__ u1,
                        u16* __restrict__ h1, int n1,
                        const u16* __restrict__ g2, const u16* __restrict__ u2,
                        u16* __restrict__ h2, int n2) {
  int i = blockIdx.x * 256 + threadIdx.x;
  const u16 *g, *u; u16* h; int idx;
  if (i < n1) { g = g1; u = u1; h = h1; idx = i; }
  else { idx = i - n1; if (idx >= n2) return; g = g2; u = u2; h = h2; }
  s16x8 gv = ((const s16x8*)g)[idx];
  s16x8 uv = ((const s16x8*)u)[idx];
  s16x8 hv;
#pragma unroll
  for (int j = 0; j < 8; ++j) {
    float gf = bf2f((u16)gv[j]);
    float uf = bf2f((u16)uv[j]);
    float s = gf / (1.f + __expf(-gf));
    hv[j] = (short)f2bf(s * uf);
  }
  ((s16x8*)h)[idx] = hv;
}

// ---------------- y[t] += w0*yr[pos0] + w1*yr[pos1] ----------------
__global__ void k_combine(float* __restrict__ y, const u16* __restrict__ yr,
                          const float* __restrict__ tkw, const int* __restrict__ pos) {
  int t = blockIdx.x;
  int i = threadIdx.x;
  float w0 = tkw[2 * t], w1 = tkw[2 * t + 1];
  size_t p0 = (size_t)pos[2 * t] * DMODEL, p1 = (size_t)pos[2 * t + 1] * DMODEL;
  int d0 = i * 8;
  s16x8 a = *(const s16x8*)(yr + p0 + d0);
  s16x8 b = *(const s16x8*)(yr + p1 + d0);
  float* yo = y + (size_t)t * DMODEL + d0;
#pragma unroll
  for (int j = 0; j < 8; ++j)
    yo[j] += w0 * bf2f((u16)a[j]) + w1 * bf2f((u16)b[j]);
}

extern "C" void kernel_launch(void* const* d_in, const int* in_sizes, int n_in,
                              void* d_out, int out_size, void* d_ws, size_t ws_size,
                              hipStream_t stream) {
  const float* x   = (const float*)d_in[0];
  const float* gw  = (const float*)d_in[1];
  const float* wg  = (const float*)d_in[2];
  const float* wu  = (const float*)d_in[3];
  const float* wd  = (const float*)d_in[4];
  const float* wsg = (const float*)d_in[5];
  const float* wsu = (const float*)d_in[6];
  const float* wsd = (const float*)d_in[7];
  float* out = (float*)d_out;

  char* ws = (char*)d_ws;
  size_t o = 0;
  auto alloc = [&](size_t bytes) -> void* {
    void* p = ws + o;
    o += (bytes + 255) & ~(size_t)255;
    return p;
  };
  u16* xb   = (u16*)alloc((size_t)T_TOK * DMODEL * 2);
  u16* wbg  = (u16*)alloc((size_t)NEXP * DFF * DMODEL * 2);
  u16* wbu  = (u16*)alloc((size_t)NEXP * DFF * DMODEL * 2);
  u16* wbd  = (u16*)alloc((size_t)NEXP * DMODEL * DFF * 2);
  u16* wbsg = (u16*)alloc((size_t)DFFS * DMODEL * 2);
  u16* wbsu = (u16*)alloc((size_t)DFFS * DMODEL * 2);
  u16* wbsd = (u16*)alloc((size_t)DMODEL * DFFS * 2);
  u16* P1r  = (u16*)alloc((size_t)NSLOT * DFF * 2);    // 23.07 MB (g_r -> h_r)
  u16* P1s  = (u16*)alloc((size_t)T_TOK * DFFS * 2);   // 23.07 MB (g_s -> h_s)
  u16* P2r  = (u16*)alloc((size_t)NSLOT * DFF * 2);    // u_r; aliased by yr after silu
  u16* P2s  = (u16*)alloc((size_t)T_TOK * DFFS * 2);   // u_s; contiguous after P2r
  u16* yr   = P2r;  // alias: yr needs 33.6 MB <= P2r+P2s (46.1 MB); u_* dead by then
  float* tkw = (float*)alloc((size_t)T_TOK * 2 * 4);
  int* tki   = (int*)alloc((size_t)T_TOK * 2 * 4);
  int* pos   = (int*)alloc((size_t)T_TOK * 2 * 4);
  int* slot_tok = (int*)alloc((size_t)NSLOT * 4);
  int* counts   = (int*)alloc(64);
  int* offs     = (int*)alloc(64);
  int* cursor   = (int*)alloc(64);
  int* tblGU    = (int*)alloc(GU_GRID * 4);
  int* tblDN    = (int*)alloc(DN_GRID * 4);
  int* nact     = (int*)alloc(64);
  if (o > ws_size) {
    fprintf(stderr, "kernel_launch: ws too small: need %zu have %zu\n", o, ws_size);
    return;
  }

  // --- merged weight conversion (single dispatch, grid-stride) ---
  {
    int n8w = NEXP * DFF * DMODEL / 8;
    int n8s = DFFS * DMODEL / 8;
    k_convert6<<<2048, 256, 0, stream>>>(wg, wbg, n8w, wu, wbu, n8w, wd, wbd, n8w,
                                         wsg, wbsg, n8s, wsu, wbsu, n8s, wsd, wbsd, n8s);
  }

  // --- routing (also produces xb) + schedule tables ---
  k_zero<<<1, 64, 0, stream>>>(counts);
  k_router<<<T_TOK, 256, 0, stream>>>(x, gw, xb, tkw, tki, counts);
  k_scan_sched<<<1, 64, 0, stream>>>(counts, offs, cursor, tblGU, tblDN, nact);
  k_assign<<<(T_TOK + 255) / 256, 256, 0, stream>>>(tki, cursor, pos, slot_tok);

  // --- merged gate/up GEMM (routed + shared) ---
  k_gemm8<0><<<GU_GRID, 512, 0, stream>>>(
      tblGU, nact, xb, nullptr, nullptr,
      wbg, wbu, wbd, wbsg, wbsu, wbsd,
      P1r, P2r, P1s, P2s, yr, out, offs, counts, slot_tok);

  // --- merged silu ---
  {
    int n1 = NSLOT * DFF / 8, n2 = T_TOK * DFFS / 8;
    k_silu2<<<(n1 + n2 + 255) / 256, 256, 0, stream>>>(
        P1r, P2r, P1r, n1, P1s, P2s, P1s, n2);
  }

  // --- merged down GEMM (routed -> yr, shared -> out) ---
  k_gemm8<1><<<DN_GRID, 512, 0, stream>>>(
      tblDN, nact, xb, P1r, P1s,
      wbg, wbu, wbd, wbsg, wbsu, wbsd,
      P1r, P2r, P1s, P2s, yr, out, offs, counts, slot_tok);

  // --- combine routed into output ---
  k_combine<<<T_TOK, 256, 0, stream>>>(out, yr, tkw, pos);
}